// Round 9
// baseline (209.322 us; speedup 1.0000x reference)
//
#include <hip/hip_runtime.h>
#include <cstdint>
#include <cstddef>

#define DIMC 768
#define NHH  12
#define NSEQ 1024
#define HD   64

#define SX  6291456   // x elems (8*1024*768)
#define SW1 1769472   // qkv_w elems
#define SW2 589824    // proj_w elems

#define RELN 3969     // 63*63 table entries per head
#define RELP 4032     // padded stride

#define NCAST ((SX + SW1 + SW2) / 2048)       // 4224 cast blocks
#define NRELB ((NHH * RELN + 255) / 256)      // 187 relt blocks

#define LOG2E 1.4426950408889634f

typedef _Float16 f16x8 __attribute__((ext_vector_type(8)));
typedef _Float16 f16x4 __attribute__((ext_vector_type(4)));
typedef float    f32x4 __attribute__((ext_vector_type(4)));
typedef float    f32x16 __attribute__((ext_vector_type(16)));

__device__ inline void gld16(const void* g, void* l) {
  __builtin_amdgcn_global_load_lds(
      (const __attribute__((address_space(1))) void*)g,
      (__attribute__((address_space(3))) void*)l, 16, 0, 0);
}

// ---------------------------------------------------------------------------
// Fused fp32 -> fp16 cast of x | qkv_w | proj_w into one contiguous ws region,
// PLUS (tail blocks) the head-major relative-bias transpose.  Round 16: relT
// is pre-scaled by log2e so flash can use native exp2 (v_exp_f32) with no
// per-element multiply; the matching log2e factor on S goes into the Q scale.
// ---------------------------------------------------------------------------
__global__ __launch_bounds__(256) void cast_f16(
    const float* __restrict__ x, const float* __restrict__ w1,
    const float* __restrict__ w2, _Float16* __restrict__ dst,
    const float* __restrict__ rel_table, float* __restrict__ relT) {
  if (blockIdx.x >= NCAST) {                  // relT transpose tail
    const int g = (blockIdx.x - NCAST) * 256 + threadIdx.x;
    if (g < NHH * RELN) {
      const int h = g / RELN, idx = g - h * RELN;
      relT[h * RELP + idx] = rel_table[idx * NHH + h] * LOG2E;
    }
    return;
  }
  const long long t = (long long)blockIdx.x * 256 + threadIdx.x;
  const long long i = t * 8;
  const float* src; long long off;
  if (i < SX) { src = x; off = i; }
  else if (i < SX + SW1) { src = w1; off = i - SX; }
  else { src = w2; off = i - (SX + SW1); }
  const float4 a = *(const float4*)(src + off);
  const float4 b = *(const float4*)(src + off + 4);
  f16x8 o;
  o[0] = (_Float16)a.x; o[1] = (_Float16)a.y; o[2] = (_Float16)a.z; o[3] = (_Float16)a.w;
  o[4] = (_Float16)b.x; o[5] = (_Float16)b.y; o[6] = (_Float16)b.z; o[7] = (_Float16)b.w;
  *(f16x8*)(dst + i) = o;
}

// ---------------------------------------------------------------------------
// MFMA GEMM: C[m,o] = sum_k A[m,k]*W[o,k].  128x128 tile, BK=64 (r8 config,
// kept: gemm ledger plateaued 54-55us across 4 structures; no more surgery).
// Single buffer, two barriers, compiler-scheduled; T2 8-chunk involution
// swizzle (bank conflicts 0).  1-D grid, XCD-swizzled: m_idx = n & 63.
// EPI==0: scatter f16 Q(+bias, *0.125*log2e), K, V->Vt transposed.
// EPI==1: fp32 outF = acc + b0[o].
// ---------------------------------------------------------------------------
template <int EPI>
__global__ __launch_bounds__(256) void gemm_mfma(
    const _Float16* __restrict__ A, const _Float16* __restrict__ W,
    const float* __restrict__ b0, const float* __restrict__ b1,
    float* __restrict__ outF, _Float16* __restrict__ oq,
    _Float16* __restrict__ ok, _Float16* __restrict__ ovt) {
  __shared__ _Float16 Alds[128 * 64];
  __shared__ _Float16 Blds[128 * 64];

  const int tid = threadIdx.x;
  const int w = tid >> 6, lane = tid & 63, quad = lane >> 4, l16 = lane & 15;
  const int m0 = (blockIdx.x & 63) << 7;
  const int o0 = (blockIdx.x >> 6) << 7;
  const int wr = (w >> 1) * 64, wc = (w & 1) * 64;
  const int rkey = l16 & 7;                   // read-side swizzle key

  f32x4 acc[4][4];
#pragma unroll
  for (int i = 0; i < 4; i++)
#pragma unroll
    for (int j = 0; j < 4; j++) acc[i][j] = (f32x4){0.f, 0.f, 0.f, 0.f};

  // staging: slot c = tid + k*256 (k=0..3) -> row = (tid>>3)+32k, chunk = tid&7.
  // Global source chunk = (tid&7) ^ (row&7); row&7 == (tid>>3)&7 for all k.
  const int srow = tid >> 3;
  const int sch = ((tid & 7) ^ (srow & 7)) * 8;
  const _Float16* Ap = A + (size_t)(m0 + srow) * DIMC + sch;
  const _Float16* Wp = W + (size_t)(o0 + srow) * DIMC + sch;
  _Float16* Adst = &Alds[tid * 8];
  _Float16* Bdst = &Blds[tid * 8];

  for (int k0 = 0; k0 < DIMC; k0 += 64) {
    __syncthreads();
#pragma unroll
    for (int k = 0; k < 4; k++) {
      gld16(Ap + k0 + k * 32 * DIMC, Adst + k * 2048);
      gld16(Wp + k0 + k * 32 * DIMC, Bdst + k * 2048);
    }
    __syncthreads();                          // vmcnt drained -> tile visible

#pragma unroll
    for (int ks = 0; ks < 2; ks++) {
      const int ch = (((ks << 2) + quad) ^ rkey) * 8;
      f16x8 a[4], b[4];
#pragma unroll
      for (int i = 0; i < 4; i++)
        a[i] = *(const f16x8*)&Alds[(wr + i * 16 + l16) * 64 + ch];
#pragma unroll
      for (int j = 0; j < 4; j++)
        b[j] = *(const f16x8*)&Blds[(wc + j * 16 + l16) * 64 + ch];
#pragma unroll
      for (int i = 0; i < 4; i++)
#pragma unroll
        for (int j = 0; j < 4; j++)
          acc[i][j] = __builtin_amdgcn_mfma_f32_16x16x32_f16(a[i], b[j], acc[i][j], 0, 0, 0);
    }
  }

  if constexpr (EPI == 0) {
#pragma unroll
    for (int j = 0; j < 4; j++) {
      const int o = o0 + wc + j * 16 + l16;
      const int part = o / DIMC;
      const int cc = o - part * DIMC;
      const int hh = cc >> 6, d = cc & 63;
      const float badd = (part == 0) ? b0[cc] : (part == 2 ? b1[cc] : 0.f);
      if (part == 2) {
        // V: write transposed into Vt[bh][d][n], f16x4 along n
#pragma unroll
        for (int i = 0; i < 4; i++) {
          const int mb = m0 + wr + i * 16 + quad * 4;
          const int bb = mb >> 10, n0 = mb & 1023;
          f16x4 vv;
#pragma unroll
          for (int r = 0; r < 4; r++) vv[r] = (_Float16)(acc[i][j][r] + badd);
          *(f16x4*)(ovt + (((size_t)(bb * NHH + hh)) * HD + d) * NSEQ + n0) = vv;
        }
      } else {
        _Float16* dst = (part == 0) ? oq : ok;
#pragma unroll
        for (int i = 0; i < 4; i++) {
#pragma unroll
          for (int r = 0; r < 4; r++) {
            const int m = m0 + wr + i * 16 + quad * 4 + r;
            const int bb = m >> 10, n = m & 1023;
            float v = acc[i][j][r];
            if (part == 0) v = (v + badd) * (0.125f * LOG2E);
            dst[(((size_t)(bb * NHH + hh)) * NSEQ + n) * HD + d] = (_Float16)v;
          }
        }
      }
    }
  } else {
#pragma unroll
    for (int j = 0; j < 4; j++) {
      const int o = o0 + wc + j * 16 + l16;
      const float bo = b0[o];
#pragma unroll
      for (int i = 0; i < 4; i++) {
#pragma unroll
        for (int r = 0; r < 4; r++) {
          const int m = m0 + wr + i * 16 + quad * 4 + r;
          outF[(size_t)m * DIMC + o] = acc[i][j][r] + bo;
        }
      }
    }
  }
}

// ---------------------------------------------------------------------------
// Flash attention, 32x32x16 MFMA transposed compute (S^T = K Q^T, O^T = V^T P^T).
// KVBLK=64 + LDS double-buffer, single barrier per step; bias rows staged to
// LDS; register-free staging (inverse-swizzle gld_lds).
// Round 16: softmax VALU diet --
//  * bias is loaded INTO the S accumulator (MFMA C-in) instead of added
//    after: 16 v_add/t vanish into the matrix pipe, and the bias ds_reads
//    move BEFORE the MFMA cluster (off the post-MFMA critical path).
//  * p = exp2f(S): Q and relT carry the log2e factor (see cast/gemm0), so
//    the v_mul inside __expf disappears; native v_exp_f32 only.
// ---------------------------------------------------------------------------
__global__ __launch_bounds__(256, 3) void flash_mfma(
    const _Float16* __restrict__ Qg, const _Float16* __restrict__ Kg,
    const _Float16* __restrict__ Vtg, const float* __restrict__ relT,
    _Float16* __restrict__ AO) {
  const int nblk = blockIdx.x;
  const int bhl = nblk % 96;                  // same-XCD group key
  const int qt = nblk / 96;                   // 0..7 (128 q rows each)
  const int head = bhl >> 3, b = bhl & 7;
  const int bh = b * NHH + head;
  const int tid = threadIdx.x, w = tid >> 6, lane = tid & 63;
  const int ql = lane & 31;                   // q column within wave tile
  const int hf = lane >> 5;                   // lane half (k/d sub-offset)

  // double-buffered K/V tiles (KVBLK=64): 2 x (8+8) KB = 32 KB
  __shared__ _Float16 Klds[2][64 * 64];       // [row][chunk^key], 8 chunks/row
  __shared__ _Float16 Vlds[2][64 * 64];       // [d-row][chunk^key], 8 chunks/row
  __shared__ __attribute__((aligned(16))) float BiasLds[2][320];  // 5 rows x 63 + pad

  // persistent Q B-frags: B[n=ql][k = s*16 + hf*8 + j]
  const int qglob = qt * 128 + w * 32 + ql;
  const _Float16* Qrow = Qg + ((size_t)bh * NSEQ + qglob) * HD + hf * 8;
  f16x8 bq[4];
#pragma unroll
  for (int s = 0; s < 4; s++) bq[s] = *(const f16x8*)(Qrow + s * 16);

  f32x16 O0 = {}, O1 = {};                    // O^T d-tiles 0..31, 32..63
  float psum = 0.f;

  const _Float16* Kbase = Kg + (size_t)bh * NSEQ * HD;
  const _Float16* Vtbase = Vtg + (size_t)bh * HD * NSEQ;

  // bias: qy fixed per wave; dy = qy - tau + 31, tau = 2*step + t
  const float* relTh = relT + (size_t)head * RELP;
  const int idxb = ql + 31 - 4 * hf;          // dx = idxb - (r&3) - 8*(r>>2)

  // V A-frag row keys (fixed per lane)
  const int vrow0 = ql, vrow1 = 32 + ql;
  const int vkey0 = (vrow0 ^ (vrow0 >> 3)) & 7;
  const int vkey1 = (vrow1 ^ (vrow1 >> 3)) & 7;

  // staging: inverse-swizzled global offsets, linear LDS dest (involution).
  int ks0, ks1, vs0, vs1;
  {
    int c = tid;
    int r = c >> 3, cc = c & 7, key = (r ^ (r >> 3)) & 7;
    ks0 = r * HD + (cc ^ key) * 8;
    vs0 = r * NSEQ + (cc ^ key) * 8;
    c = tid + 256;
    r = c >> 3; cc = c & 7; key = (r ^ (r >> 3)) & 7;
    ks1 = r * HD + (cc ^ key) * 8;
    vs1 = r * NSEQ + (cc ^ key) * 8;
  }

  // stage step s into buffer bsel (K 8KB + V 8KB + bias 316 floats)
  auto stage = [&](int s, int bsel) {
    const _Float16* Ks = Kbase + (size_t)s * 64 * HD;
    const _Float16* Vs = Vtbase + s * 64;
    gld16(Ks + ks0, &Klds[bsel][tid * 8]);
    gld16(Ks + ks1, &Klds[bsel][(tid + 256) * 8]);
    gld16(Vs + vs0, &Vlds[bsel][tid * 8]);
    gld16(Vs + vs1, &Vlds[bsel][(tid + 256) * 8]);
    if (tid < 79) {                           // 79*4 = 316 floats, contiguous
      const int dyLo = qt * 4 + 30 - 2 * s;   // in [0, 58]; span <= RELP pad
      gld16(relTh + dyLo * 63 + tid * 4, &BiasLds[bsel][tid * 4]);
    }
  };

  stage(0, 0);                                // prologue (only exposed latency)

  int cur = 0;
#pragma unroll 2
  for (int s = 0; s < 16; s++) {
    __syncthreads();                          // drains own vmcnt -> buf[cur] ready
    if (s + 1 < 16) stage(s + 1, cur ^ 1);    // in flight under compute(s)

#pragma unroll
    for (int t = 0; t < 2; t++) {
      // bias -> S accumulator (MFMA C-in); reads issue before the MFMA
      // cluster, latency covered by surrounding VALU/MFMA of adjacent tiles.
      // p_j of group g needs relT row entry [idxb - 8g - j].
      const float* lb = &BiasLds[cur][(w + 1 - t) * 63 + idxb];
      f32x16 S;
#pragma unroll
      for (int g = 0; g < 4; g++) {
        S[4 * g + 0] = lb[-8 * g - 0];
        S[4 * g + 1] = lb[-8 * g - 1];
        S[4 * g + 2] = lb[-8 * g - 2];
        S[4 * g + 3] = lb[-8 * g - 3];
      }

      // S^T 32x32 tile: A = K rows (t*32+ql), contraction d (64)
      const int arow = t * 32 + ql;
      const int akey = (arow ^ (arow >> 3)) & 7;
      __builtin_amdgcn_s_setprio(1);
#pragma unroll
      for (int ss = 0; ss < 4; ss++) {
        const f16x8 ak = *(const f16x8*)&Klds[cur][((arow << 3) | ((ss * 2 + hf) ^ akey)) * 8];
        S = __builtin_amdgcn_mfma_f32_32x32x16_f16(ak, bq[ss], S, 0, 0, 0);
      }
      __builtin_amdgcn_s_setprio(0);

      // exp2 (native v_exp_f32; log2e folded into Q and relT) + psum + pack
      unsigned int dw[8];
#pragma unroll
      for (int g = 0; g < 4; g++) {
        const float p0 = exp2f(S[4 * g + 0]);
        const float p1 = exp2f(S[4 * g + 1]);
        const float p2 = exp2f(S[4 * g + 2]);
        const float p3 = exp2f(S[4 * g + 3]);
        psum += (p0 + p1) + (p2 + p3);
        union { f16x4 h; unsigned int u[2]; } cv;
        cv.h[0] = (_Float16)p0; cv.h[1] = (_Float16)p1;
        cv.h[2] = (_Float16)p2; cv.h[3] = (_Float16)p3;
        dw[2 * g] = cv.u[0]; dw[2 * g + 1] = cv.u[1];
      }

      // PV: B-frag from P^T via half-exchange; A = V^T rows from LDS
      __builtin_amdgcn_s_setprio(1);
#pragma unroll
      for (int s2 = 0; s2 < 2; s2++) {
        const unsigned int x0 = hf ? dw[4 * s2 + 0] : dw[4 * s2 + 2];
        const unsigned int x1 = hf ? dw[4 * s2 + 1] : dw[4 * s2 + 3];
        const unsigned int y0 = (unsigned int)__shfl_xor((int)x0, 32, 64);
        const unsigned int y1 = (unsigned int)__shfl_xor((int)x1, 32, 64);
        union { unsigned int u[4]; f16x8 v; } bp;
        if (hf == 0) {
          bp.u[0] = dw[4 * s2 + 0]; bp.u[1] = dw[4 * s2 + 1];
          bp.u[2] = y0;             bp.u[3] = y1;
        } else {
          bp.u[0] = y0;             bp.u[1] = y1;
          bp.u[2] = dw[4 * s2 + 2]; bp.u[3] = dw[4 * s2 + 3];
        }
        const int kchunk = t * 4 + s2 * 2 + hf;
        const f16x8 av0 = *(const f16x8*)&Vlds[cur][((vrow0 << 3) | (kchunk ^ vkey0)) * 8];
        O0 = __builtin_amdgcn_mfma_f32_32x32x16_f16(av0, bp.v, O0, 0, 0, 0);
        const f16x8 av1 = *(const f16x8*)&Vlds[cur][((vrow1 << 3) | (kchunk ^ vkey1)) * 8];
        O1 = __builtin_amdgcn_mfma_f32_32x32x16_f16(av1, bp.v, O1, 0, 0, 0);
      }
      __builtin_amdgcn_s_setprio(0);
    }
    cur ^= 1;
  }

  // total row-sum for this lane's q column; divide + store O^T
  psum += __shfl_xor(psum, 32, 64);
  const float inv = 1.f / psum;
  _Float16* aoRow = AO + ((size_t)(b * NSEQ + qglob)) * DIMC + head * HD;
#pragma unroll
  for (int g = 0; g < 4; g++) {
    f16x4 o0, o1;
#pragma unroll
    for (int j = 0; j < 4; j++) {
      o0[j] = (_Float16)(O0[4 * g + j] * inv);
      o1[j] = (_Float16)(O1[4 * g + j] * inv);
    }
    const int d0 = 8 * g + 4 * hf;
    *(f16x4*)(aoRow + d0) = o0;
    *(f16x4*)(aoRow + 32 + d0) = o1;
  }
}

extern "C" void kernel_launch(void* const* d_in, const int* in_sizes, int n_in,
                              void* d_out, int out_size, void* d_ws, size_t ws_size,
                              hipStream_t stream) {
  const float* x        = (const float*)d_in[0];
  const float* qkv_w    = (const float*)d_in[1];
  const float* q_bias   = (const float*)d_in[2];
  const float* v_bias   = (const float*)d_in[3];
  const float* proj_w   = (const float*)d_in[4];
  const float* proj_b   = (const float*)d_in[5];
  const float* rel_tab  = (const float*)d_in[6];
  float* out = (float*)d_out;

  const size_t NTOK = (size_t)8 * NHH * NSEQ * HD;
  _Float16* Xb     = (_Float16*)d_ws;
  _Float16* Wqkvb  = Xb + SX;
  _Float16* Wprojb = Wqkvb + SW1;
  _Float16* Qb     = Wprojb + SW2;
  _Float16* Kb     = Qb + NTOK;
  _Float16* Vt     = Kb + NTOK;             // V written transposed by qkv gemm
  float*    relT   = (float*)(Vt + NTOK);   // 12*4032 fp32 = 193 KB
  _Float16* AOb    = Xb;                    // alias: x consumed before flash writes

  cast_f16<<<dim3(NCAST + NRELB), 256, 0, stream>>>(x, qkv_w, proj_w, Xb,
                                                    rel_tab, relT);

  gemm_mfma<0><<<dim3(64 * 18), 256, 0, stream>>>(
      Xb, Wqkvb, q_bias, v_bias, nullptr, Qb, Kb, Vt);

  flash_mfma<<<dim3(768), 256, 0, stream>>>(Qb, Kb, Vt, relT, AOb);

  gemm_mfma<1><<<dim3(64 * 6), 256, 0, stream>>>(
      AOb, Wprojb, proj_b, nullptr, out, nullptr, nullptr, nullptr);
}

// Round 10
// 198.376 us; speedup vs baseline: 1.0552x; 1.0552x over previous
//
#include <hip/hip_runtime.h>
#include <cstdint>
#include <cstddef>

#define DIMC 768
#define NHH  12
#define NSEQ 1024
#define HD   64

#define SX  6291456   // x elems (8*1024*768)
#define SW1 1769472   // qkv_w elems
#define SW2 589824    // proj_w elems

#define RELN 3969     // 63*63 table entries per head
#define RELP 4032     // padded stride

#define NCAST ((SX + SW1 + SW2) / 2048)       // 4224 cast blocks
#define NRELB ((NHH * RELN + 255) / 256)      // 187 relt blocks

#define LOG2E 1.4426950408889634f

typedef _Float16 f16x8 __attribute__((ext_vector_type(8)));
typedef _Float16 f16x4 __attribute__((ext_vector_type(4)));
typedef float    f32x4 __attribute__((ext_vector_type(4)));
typedef float    f32x16 __attribute__((ext_vector_type(16)));

__device__ inline void gld16(const void* g, void* l) {
  __builtin_amdgcn_global_load_lds(
      (const __attribute__((address_space(1))) void*)g,
      (__attribute__((address_space(3))) void*)l, 16, 0, 0);
}

// ---------------------------------------------------------------------------
// Fused fp32 -> fp16 cast of x | qkv_w | proj_w into one contiguous ws region,
// PLUS (tail blocks) the head-major relative-bias transpose.  relT is
// pre-scaled by log2e so flash can use native exp2 (v_exp_f32) with no
// per-element multiply; the matching log2e factor on S goes into the Q scale.
// ---------------------------------------------------------------------------
__global__ __launch_bounds__(256) void cast_f16(
    const float* __restrict__ x, const float* __restrict__ w1,
    const float* __restrict__ w2, _Float16* __restrict__ dst,
    const float* __restrict__ rel_table, float* __restrict__ relT) {
  if (blockIdx.x >= NCAST) {                  // relT transpose tail
    const int g = (blockIdx.x - NCAST) * 256 + threadIdx.x;
    if (g < NHH * RELN) {
      const int h = g / RELN, idx = g - h * RELN;
      relT[h * RELP + idx] = rel_table[idx * NHH + h] * LOG2E;
    }
    return;
  }
  const long long t = (long long)blockIdx.x * 256 + threadIdx.x;
  const long long i = t * 8;
  const float* src; long long off;
  if (i < SX) { src = x; off = i; }
  else if (i < SX + SW1) { src = w1; off = i - SX; }
  else { src = w2; off = i - (SX + SW1); }
  const float4 a = *(const float4*)(src + off);
  const float4 b = *(const float4*)(src + off + 4);
  f16x8 o;
  o[0] = (_Float16)a.x; o[1] = (_Float16)a.y; o[2] = (_Float16)a.z; o[3] = (_Float16)a.w;
  o[4] = (_Float16)b.x; o[5] = (_Float16)b.y; o[6] = (_Float16)b.z; o[7] = (_Float16)b.w;
  *(f16x8*)(dst + i) = o;
}

// ---------------------------------------------------------------------------
// MFMA GEMM: C[m,o] = sum_k A[m,k]*W[o,k].  128x128 tile, BK=64 (r8 config,
// kept: gemm ledger plateaued 54-55us across 4 structures; no more surgery).
// Single buffer, two barriers, compiler-scheduled; T2 8-chunk involution
// swizzle (bank conflicts 0).  1-D grid, XCD-swizzled: m_idx = n & 63.
// EPI==0: scatter f16 Q(+bias, *0.125*log2e), K, V->Vt transposed.
// EPI==1: fp32 outF = acc + b0[o].
// ---------------------------------------------------------------------------
template <int EPI>
__global__ __launch_bounds__(256) void gemm_mfma(
    const _Float16* __restrict__ A, const _Float16* __restrict__ W,
    const float* __restrict__ b0, const float* __restrict__ b1,
    float* __restrict__ outF, _Float16* __restrict__ oq,
    _Float16* __restrict__ ok, _Float16* __restrict__ ovt) {
  __shared__ _Float16 Alds[128 * 64];
  __shared__ _Float16 Blds[128 * 64];

  const int tid = threadIdx.x;
  const int w = tid >> 6, lane = tid & 63, quad = lane >> 4, l16 = lane & 15;
  const int m0 = (blockIdx.x & 63) << 7;
  const int o0 = (blockIdx.x >> 6) << 7;
  const int wr = (w >> 1) * 64, wc = (w & 1) * 64;
  const int rkey = l16 & 7;                   // read-side swizzle key

  f32x4 acc[4][4];
#pragma unroll
  for (int i = 0; i < 4; i++)
#pragma unroll
    for (int j = 0; j < 4; j++) acc[i][j] = (f32x4){0.f, 0.f, 0.f, 0.f};

  // staging: slot c = tid + k*256 (k=0..3) -> row = (tid>>3)+32k, chunk = tid&7.
  // Global source chunk = (tid&7) ^ (row&7); row&7 == (tid>>3)&7 for all k.
  const int srow = tid >> 3;
  const int sch = ((tid & 7) ^ (srow & 7)) * 8;
  const _Float16* Ap = A + (size_t)(m0 + srow) * DIMC + sch;
  const _Float16* Wp = W + (size_t)(o0 + srow) * DIMC + sch;
  _Float16* Adst = &Alds[tid * 8];
  _Float16* Bdst = &Blds[tid * 8];

  for (int k0 = 0; k0 < DIMC; k0 += 64) {
    __syncthreads();
#pragma unroll
    for (int k = 0; k < 4; k++) {
      gld16(Ap + k0 + k * 32 * DIMC, Adst + k * 2048);
      gld16(Wp + k0 + k * 32 * DIMC, Bdst + k * 2048);
    }
    __syncthreads();                          // vmcnt drained -> tile visible

#pragma unroll
    for (int ks = 0; ks < 2; ks++) {
      const int ch = (((ks << 2) + quad) ^ rkey) * 8;
      f16x8 a[4], b[4];
#pragma unroll
      for (int i = 0; i < 4; i++)
        a[i] = *(const f16x8*)&Alds[(wr + i * 16 + l16) * 64 + ch];
#pragma unroll
      for (int j = 0; j < 4; j++)
        b[j] = *(const f16x8*)&Blds[(wc + j * 16 + l16) * 64 + ch];
#pragma unroll
      for (int i = 0; i < 4; i++)
#pragma unroll
        for (int j = 0; j < 4; j++)
          acc[i][j] = __builtin_amdgcn_mfma_f32_16x16x32_f16(a[i], b[j], acc[i][j], 0, 0, 0);
    }
  }

  if constexpr (EPI == 0) {
#pragma unroll
    for (int j = 0; j < 4; j++) {
      const int o = o0 + wc + j * 16 + l16;
      const int part = o / DIMC;
      const int cc = o - part * DIMC;
      const int hh = cc >> 6, d = cc & 63;
      const float badd = (part == 0) ? b0[cc] : (part == 2 ? b1[cc] : 0.f);
      if (part == 2) {
        // V: write transposed into Vt[bh][d][n], f16x4 along n
#pragma unroll
        for (int i = 0; i < 4; i++) {
          const int mb = m0 + wr + i * 16 + quad * 4;
          const int bb = mb >> 10, n0 = mb & 1023;
          f16x4 vv;
#pragma unroll
          for (int r = 0; r < 4; r++) vv[r] = (_Float16)(acc[i][j][r] + badd);
          *(f16x4*)(ovt + (((size_t)(bb * NHH + hh)) * HD + d) * NSEQ + n0) = vv;
        }
      } else {
        _Float16* dst = (part == 0) ? oq : ok;
#pragma unroll
        for (int i = 0; i < 4; i++) {
#pragma unroll
          for (int r = 0; r < 4; r++) {
            const int m = m0 + wr + i * 16 + quad * 4 + r;
            const int bb = m >> 10, n = m & 1023;
            float v = acc[i][j][r];
            if (part == 0) v = (v + badd) * (0.125f * LOG2E);
            dst[(((size_t)(bb * NHH + hh)) * NSEQ + n) * HD + d] = (_Float16)v;
          }
        }
      }
    }
  } else {
#pragma unroll
    for (int j = 0; j < 4; j++) {
      const int o = o0 + wc + j * 16 + l16;
      const float bo = b0[o];
#pragma unroll
      for (int i = 0; i < 4; i++) {
#pragma unroll
        for (int r = 0; r < 4; r++) {
          const int m = m0 + wr + i * 16 + quad * 4 + r;
          outF[(size_t)m * DIMC + o] = acc[i][j][r] + bo;
        }
      }
    }
  }
}

// ---------------------------------------------------------------------------
// Flash attention, 32x32x16 MFMA transposed compute (S^T = K Q^T, O^T = V^T P^T).
// KVBLK=64 + LDS double-buffer, single barrier per step; bias rows staged to
// LDS; register-free staging (inverse-swizzle gld_lds).
// Round 17 fix of r16's regression: bare exp2f() lowered to the PRECISE
// __ocml_exp2_f32 path (no -ffast-math) -> ~10+ VALU/call, VALUBusy 32->55,
// flash +6us.  Replace with __builtin_amdgcn_exp2f = single v_exp_f32
// (D = 2^S0, ISA table 3).  Bias-in-C and log2e folding kept (absmax was
// unchanged at 2.44e-4; those parts are correct and cheap).
// ---------------------------------------------------------------------------
__global__ __launch_bounds__(256, 3) void flash_mfma(
    const _Float16* __restrict__ Qg, const _Float16* __restrict__ Kg,
    const _Float16* __restrict__ Vtg, const float* __restrict__ relT,
    _Float16* __restrict__ AO) {
  const int nblk = blockIdx.x;
  const int bhl = nblk % 96;                  // same-XCD group key
  const int qt = nblk / 96;                   // 0..7 (128 q rows each)
  const int head = bhl >> 3, b = bhl & 7;
  const int bh = b * NHH + head;
  const int tid = threadIdx.x, w = tid >> 6, lane = tid & 63;
  const int ql = lane & 31;                   // q column within wave tile
  const int hf = lane >> 5;                   // lane half (k/d sub-offset)

  // double-buffered K/V tiles (KVBLK=64): 2 x (8+8) KB = 32 KB
  __shared__ _Float16 Klds[2][64 * 64];       // [row][chunk^key], 8 chunks/row
  __shared__ _Float16 Vlds[2][64 * 64];       // [d-row][chunk^key], 8 chunks/row
  __shared__ __attribute__((aligned(16))) float BiasLds[2][320];  // 5 rows x 63 + pad

  // persistent Q B-frags: B[n=ql][k = s*16 + hf*8 + j]
  const int qglob = qt * 128 + w * 32 + ql;
  const _Float16* Qrow = Qg + ((size_t)bh * NSEQ + qglob) * HD + hf * 8;
  f16x8 bq[4];
#pragma unroll
  for (int s = 0; s < 4; s++) bq[s] = *(const f16x8*)(Qrow + s * 16);

  f32x16 O0 = {}, O1 = {};                    // O^T d-tiles 0..31, 32..63
  float psum = 0.f;

  const _Float16* Kbase = Kg + (size_t)bh * NSEQ * HD;
  const _Float16* Vtbase = Vtg + (size_t)bh * HD * NSEQ;

  // bias: qy fixed per wave; dy = qy - tau + 31, tau = 2*step + t
  const float* relTh = relT + (size_t)head * RELP;
  const int idxb = ql + 31 - 4 * hf;          // dx = idxb - (r&3) - 8*(r>>2)

  // V A-frag row keys (fixed per lane)
  const int vrow0 = ql, vrow1 = 32 + ql;
  const int vkey0 = (vrow0 ^ (vrow0 >> 3)) & 7;
  const int vkey1 = (vrow1 ^ (vrow1 >> 3)) & 7;

  // staging: inverse-swizzled global offsets, linear LDS dest (involution).
  int ks0, ks1, vs0, vs1;
  {
    int c = tid;
    int r = c >> 3, cc = c & 7, key = (r ^ (r >> 3)) & 7;
    ks0 = r * HD + (cc ^ key) * 8;
    vs0 = r * NSEQ + (cc ^ key) * 8;
    c = tid + 256;
    r = c >> 3; cc = c & 7; key = (r ^ (r >> 3)) & 7;
    ks1 = r * HD + (cc ^ key) * 8;
    vs1 = r * NSEQ + (cc ^ key) * 8;
  }

  // stage step s into buffer bsel (K 8KB + V 8KB + bias 316 floats)
  auto stage = [&](int s, int bsel) {
    const _Float16* Ks = Kbase + (size_t)s * 64 * HD;
    const _Float16* Vs = Vtbase + s * 64;
    gld16(Ks + ks0, &Klds[bsel][tid * 8]);
    gld16(Ks + ks1, &Klds[bsel][(tid + 256) * 8]);
    gld16(Vs + vs0, &Vlds[bsel][tid * 8]);
    gld16(Vs + vs1, &Vlds[bsel][(tid + 256) * 8]);
    if (tid < 79) {                           // 79*4 = 316 floats, contiguous
      const int dyLo = qt * 4 + 30 - 2 * s;   // in [0, 58]; span <= RELP pad
      gld16(relTh + dyLo * 63 + tid * 4, &BiasLds[bsel][tid * 4]);
    }
  };

  stage(0, 0);                                // prologue (only exposed latency)

  int cur = 0;
#pragma unroll 2
  for (int s = 0; s < 16; s++) {
    __syncthreads();                          // drains own vmcnt -> buf[cur] ready
    if (s + 1 < 16) stage(s + 1, cur ^ 1);    // in flight under compute(s)

#pragma unroll
    for (int t = 0; t < 2; t++) {
      // bias -> S accumulator (MFMA C-in); reads issue before the MFMA
      // cluster, latency covered by surrounding VALU/MFMA of adjacent tiles.
      // p_j of group g needs relT row entry [idxb - 8g - j].
      const float* lb = &BiasLds[cur][(w + 1 - t) * 63 + idxb];
      f32x16 S;
#pragma unroll
      for (int g = 0; g < 4; g++) {
        S[4 * g + 0] = lb[-8 * g - 0];
        S[4 * g + 1] = lb[-8 * g - 1];
        S[4 * g + 2] = lb[-8 * g - 2];
        S[4 * g + 3] = lb[-8 * g - 3];
      }

      // S^T 32x32 tile: A = K rows (t*32+ql), contraction d (64)
      const int arow = t * 32 + ql;
      const int akey = (arow ^ (arow >> 3)) & 7;
      __builtin_amdgcn_s_setprio(1);
#pragma unroll
      for (int ss = 0; ss < 4; ss++) {
        const f16x8 ak = *(const f16x8*)&Klds[cur][((arow << 3) | ((ss * 2 + hf) ^ akey)) * 8];
        S = __builtin_amdgcn_mfma_f32_32x32x16_f16(ak, bq[ss], S, 0, 0, 0);
      }
      __builtin_amdgcn_s_setprio(0);

      // native exp2 (v_exp_f32; log2e folded into Q and relT) + psum + pack
      unsigned int dw[8];
#pragma unroll
      for (int g = 0; g < 4; g++) {
        const float p0 = __builtin_amdgcn_exp2f(S[4 * g + 0]);
        const float p1 = __builtin_amdgcn_exp2f(S[4 * g + 1]);
        const float p2 = __builtin_amdgcn_exp2f(S[4 * g + 2]);
        const float p3 = __builtin_amdgcn_exp2f(S[4 * g + 3]);
        psum += (p0 + p1) + (p2 + p3);
        union { f16x4 h; unsigned int u[2]; } cv;
        cv.h[0] = (_Float16)p0; cv.h[1] = (_Float16)p1;
        cv.h[2] = (_Float16)p2; cv.h[3] = (_Float16)p3;
        dw[2 * g] = cv.u[0]; dw[2 * g + 1] = cv.u[1];
      }

      // PV: B-frag from P^T via half-exchange; A = V^T rows from LDS
      __builtin_amdgcn_s_setprio(1);
#pragma unroll
      for (int s2 = 0; s2 < 2; s2++) {
        const unsigned int x0 = hf ? dw[4 * s2 + 0] : dw[4 * s2 + 2];
        const unsigned int x1 = hf ? dw[4 * s2 + 1] : dw[4 * s2 + 3];
        const unsigned int y0 = (unsigned int)__shfl_xor((int)x0, 32, 64);
        const unsigned int y1 = (unsigned int)__shfl_xor((int)x1, 32, 64);
        union { unsigned int u[4]; f16x8 v; } bp;
        if (hf == 0) {
          bp.u[0] = dw[4 * s2 + 0]; bp.u[1] = dw[4 * s2 + 1];
          bp.u[2] = y0;             bp.u[3] = y1;
        } else {
          bp.u[0] = y0;             bp.u[1] = y1;
          bp.u[2] = dw[4 * s2 + 2]; bp.u[3] = dw[4 * s2 + 3];
        }
        const int kchunk = t * 4 + s2 * 2 + hf;
        const f16x8 av0 = *(const f16x8*)&Vlds[cur][((vrow0 << 3) | (kchunk ^ vkey0)) * 8];
        O0 = __builtin_amdgcn_mfma_f32_32x32x16_f16(av0, bp.v, O0, 0, 0, 0);
        const f16x8 av1 = *(const f16x8*)&Vlds[cur][((vrow1 << 3) | (kchunk ^ vkey1)) * 8];
        O1 = __builtin_amdgcn_mfma_f32_32x32x16_f16(av1, bp.v, O1, 0, 0, 0);
      }
      __builtin_amdgcn_s_setprio(0);
    }
    cur ^= 1;
  }

  // total row-sum for this lane's q column; divide + store O^T
  psum += __shfl_xor(psum, 32, 64);
  const float inv = 1.f / psum;
  _Float16* aoRow = AO + ((size_t)(b * NSEQ + qglob)) * DIMC + head * HD;
#pragma unroll
  for (int g = 0; g < 4; g++) {
    f16x4 o0, o1;
#pragma unroll
    for (int j = 0; j < 4; j++) {
      o0[j] = (_Float16)(O0[4 * g + j] * inv);
      o1[j] = (_Float16)(O1[4 * g + j] * inv);
    }
    const int d0 = 8 * g + 4 * hf;
    *(f16x4*)(aoRow + d0) = o0;
    *(f16x4*)(aoRow + 32 + d0) = o1;
  }
}

extern "C" void kernel_launch(void* const* d_in, const int* in_sizes, int n_in,
                              void* d_out, int out_size, void* d_ws, size_t ws_size,
                              hipStream_t stream) {
  const float* x        = (const float*)d_in[0];
  const float* qkv_w    = (const float*)d_in[1];
  const float* q_bias   = (const float*)d_in[2];
  const float* v_bias   = (const float*)d_in[3];
  const float* proj_w   = (const float*)d_in[4];
  const float* proj_b   = (const float*)d_in[5];
  const float* rel_tab  = (const float*)d_in[6];
  float* out = (float*)d_out;

  const size_t NTOK = (size_t)8 * NHH * NSEQ * HD;
  _Float16* Xb     = (_Float16*)d_ws;
  _Float16* Wqkvb  = Xb + SX;
  _Float16* Wprojb = Wqkvb + SW1;
  _Float16* Qb     = Wprojb + SW2;
  _Float16* Kb     = Qb + NTOK;
  _Float16* Vt     = Kb + NTOK;             // V written transposed by qkv gemm
  float*    relT   = (float*)(Vt + NTOK);   // 12*4032 fp32 = 193 KB
  _Float16* AOb    = Xb;                    // alias: x consumed before flash writes

  cast_f16<<<dim3(NCAST + NRELB), 256, 0, stream>>>(x, qkv_w, proj_w, Xb,
                                                    rel_tab, relT);

  gemm_mfma<0><<<dim3(64 * 18), 256, 0, stream>>>(
      Xb, Wqkvb, q_bias, v_bias, nullptr, Qb, Kb, Vt);

  flash_mfma<<<dim3(768), 256, 0, stream>>>(Qb, Kb, Vt, relT, AOb);

  gemm_mfma<1><<<dim3(64 * 6), 256, 0, stream>>>(
      AOb, Wprojb, proj_b, nullptr, out, nullptr, nullptr, nullptr);
}

// Round 11
// 193.435 us; speedup vs baseline: 1.0821x; 1.0255x over previous
//
#include <hip/hip_runtime.h>
#include <cstdint>
#include <cstddef>

#define DIMC 768
#define NHH  12
#define NSEQ 1024
#define HD   64

#define SX  6291456   // x elems (8*1024*768)
#define SW1 1769472   // qkv_w elems
#define SW2 589824    // proj_w elems

#define RELN 3969     // 63*63 table entries per head
#define RELP 4032     // padded stride

#define NCAST ((SX + SW1 + SW2) / 2048)       // 4224 cast blocks
#define NRELB ((NHH * RELN + 255) / 256)      // 187 relt blocks

#define LOG2E 1.4426950408889634f

typedef _Float16 f16x8 __attribute__((ext_vector_type(8)));
typedef _Float16 f16x4 __attribute__((ext_vector_type(4)));
typedef float    f32x4 __attribute__((ext_vector_type(4)));
typedef float    f32x16 __attribute__((ext_vector_type(16)));

__device__ inline void gld16(const void* g, void* l) {
  __builtin_amdgcn_global_load_lds(
      (const __attribute__((address_space(1))) void*)g,
      (__attribute__((address_space(3))) void*)l, 16, 0, 0);
}

// ---------------------------------------------------------------------------
// Fused fp32 -> fp16 cast of x | qkv_w | proj_w into one contiguous ws region,
// PLUS (tail blocks) the head-major relative-bias transpose.  relT is
// pre-scaled by log2e so flash can use native exp2 (v_exp_f32) with no
// per-element multiply; the matching log2e factor on S goes into the Q scale.
// ---------------------------------------------------------------------------
__global__ __launch_bounds__(256) void cast_f16(
    const float* __restrict__ x, const float* __restrict__ w1,
    const float* __restrict__ w2, _Float16* __restrict__ dst,
    const float* __restrict__ rel_table, float* __restrict__ relT) {
  if (blockIdx.x >= NCAST) {                  // relT transpose tail
    const int g = (blockIdx.x - NCAST) * 256 + threadIdx.x;
    if (g < NHH * RELN) {
      const int h = g / RELN, idx = g - h * RELN;
      relT[h * RELP + idx] = rel_table[idx * NHH + h] * LOG2E;
    }
    return;
  }
  const long long t = (long long)blockIdx.x * 256 + threadIdx.x;
  const long long i = t * 8;
  const float* src; long long off;
  if (i < SX) { src = x; off = i; }
  else if (i < SX + SW1) { src = w1; off = i - SX; }
  else { src = w2; off = i - (SX + SW1); }
  const float4 a = *(const float4*)(src + off);
  const float4 b = *(const float4*)(src + off + 4);
  f16x8 o;
  o[0] = (_Float16)a.x; o[1] = (_Float16)a.y; o[2] = (_Float16)a.z; o[3] = (_Float16)a.w;
  o[4] = (_Float16)b.x; o[5] = (_Float16)b.y; o[6] = (_Float16)b.z; o[7] = (_Float16)b.w;
  *(f16x8*)(dst + i) = o;
}

// ---------------------------------------------------------------------------
// MFMA GEMM: C[m,o] = sum_k A[m,k]*W[o,k].  Round 18: 128x64 tiles (was
// 128x128).  r10 counters (MfmaUtil 20 / VALUBusy 19 / Occupancy 15, grid
// 4.5 blk/CU with tail imbalance, gemm1 1.5 blk/CU) match the
// latency/occupancy roofline row -> bigger grid, smaller tiles.  Grid
// doubles: gemm0 2304 = 9.0/CU exact, gemm1 768 = 3.0/CU.  acc[2][4]
// (32 VGPR), LDS 24KB, 6 gld16/thread/step.  Scheduling untouched (r4/r6
// ledger: single buffer, two barriers, compiler-scheduled).  T2 8-chunk
// involution swizzle kept (conflicts 0): key srow&7 invariant across all
// 32-row staging groups for both A (4 groups) and B (2 groups).
// XCD swizzle: blockIdx%8 = m%8 -> A-panels XCD-local.
// EPI==0: scatter f16 Q(+bias, *0.125*log2e), K, V->Vt transposed.
// EPI==1: fp32 outF = acc + b0[o].
// ---------------------------------------------------------------------------
template <int EPI>
__global__ __launch_bounds__(256) void gemm_mfma(
    const _Float16* __restrict__ A, const _Float16* __restrict__ W,
    const float* __restrict__ b0, const float* __restrict__ b1,
    float* __restrict__ outF, _Float16* __restrict__ oq,
    _Float16* __restrict__ ok, _Float16* __restrict__ ovt) {
  __shared__ _Float16 Alds[128 * 64];
  __shared__ _Float16 Blds[64 * 64];

  const int tid = threadIdx.x;
  const int w = tid >> 6, lane = tid & 63, quad = lane >> 4, l16 = lane & 15;
  const int m0 = (blockIdx.x & 63) << 7;
  const int o0 = (blockIdx.x >> 6) << 6;      // 64-wide o-panel
  const int wr = w * 32;                      // wave owns 32 rows x 64 cols
  const int rkey = l16 & 7;                   // read-side swizzle key

  f32x4 acc[2][4];
#pragma unroll
  for (int i = 0; i < 2; i++)
#pragma unroll
    for (int j = 0; j < 4; j++) acc[i][j] = (f32x4){0.f, 0.f, 0.f, 0.f};

  // staging: A slots tid+k*256 (k=0..3) -> row=(tid>>3)+32k, chunk=tid&7;
  //          B slots tid+k*256 (k=0..1) -> row=(tid>>3)+32k, chunk=tid&7.
  // Global source chunk = (tid&7) ^ (row&7); row&7 == (tid>>3)&7 for all k.
  const int srow = tid >> 3;
  const int sch = ((tid & 7) ^ (srow & 7)) * 8;
  const _Float16* Ap = A + (size_t)(m0 + srow) * DIMC + sch;
  const _Float16* Wp = W + (size_t)(o0 + srow) * DIMC + sch;
  _Float16* Adst = &Alds[tid * 8];
  _Float16* Bdst = &Blds[tid * 8];

  for (int k0 = 0; k0 < DIMC; k0 += 64) {
    __syncthreads();
#pragma unroll
    for (int k = 0; k < 4; k++)
      gld16(Ap + k0 + k * 32 * DIMC, Adst + k * 2048);
#pragma unroll
    for (int k = 0; k < 2; k++)
      gld16(Wp + k0 + k * 32 * DIMC, Bdst + k * 2048);
    __syncthreads();                          // vmcnt drained -> tile visible

#pragma unroll
    for (int ks = 0; ks < 2; ks++) {
      const int ch = (((ks << 2) + quad) ^ rkey) * 8;
      f16x8 a[2], b[4];
#pragma unroll
      for (int i = 0; i < 2; i++)
        a[i] = *(const f16x8*)&Alds[(wr + i * 16 + l16) * 64 + ch];
#pragma unroll
      for (int j = 0; j < 4; j++)
        b[j] = *(const f16x8*)&Blds[(j * 16 + l16) * 64 + ch];
#pragma unroll
      for (int i = 0; i < 2; i++)
#pragma unroll
        for (int j = 0; j < 4; j++)
          acc[i][j] = __builtin_amdgcn_mfma_f32_16x16x32_f16(a[i], b[j], acc[i][j], 0, 0, 0);
    }
  }

  if constexpr (EPI == 0) {
#pragma unroll
    for (int j = 0; j < 4; j++) {
      const int o = o0 + j * 16 + l16;
      const int part = o / DIMC;
      const int cc = o - part * DIMC;
      const int hh = cc >> 6, d = cc & 63;
      const float badd = (part == 0) ? b0[cc] : (part == 2 ? b1[cc] : 0.f);
      if (part == 2) {
        // V: write transposed into Vt[bh][d][n], f16x4 along n
#pragma unroll
        for (int i = 0; i < 2; i++) {
          const int mb = m0 + wr + i * 16 + quad * 4;
          const int bb = mb >> 10, n0 = mb & 1023;
          f16x4 vv;
#pragma unroll
          for (int r = 0; r < 4; r++) vv[r] = (_Float16)(acc[i][j][r] + badd);
          *(f16x4*)(ovt + (((size_t)(bb * NHH + hh)) * HD + d) * NSEQ + n0) = vv;
        }
      } else {
        _Float16* dst = (part == 0) ? oq : ok;
#pragma unroll
        for (int i = 0; i < 2; i++) {
#pragma unroll
          for (int r = 0; r < 4; r++) {
            const int m = m0 + wr + i * 16 + quad * 4 + r;
            const int bb = m >> 10, n = m & 1023;
            float v = acc[i][j][r];
            if (part == 0) v = (v + badd) * (0.125f * LOG2E);
            dst[(((size_t)(bb * NHH + hh)) * NSEQ + n) * HD + d] = (_Float16)v;
          }
        }
      }
    }
  } else {
#pragma unroll
    for (int j = 0; j < 4; j++) {
      const int o = o0 + j * 16 + l16;
      const float bo = b0[o];
#pragma unroll
      for (int i = 0; i < 2; i++) {
#pragma unroll
        for (int r = 0; r < 4; r++) {
          const int m = m0 + wr + i * 16 + quad * 4 + r;
          outF[(size_t)m * DIMC + o] = acc[i][j][r] + bo;
        }
      }
    }
  }
}

// ---------------------------------------------------------------------------
// Flash attention, 32x32x16 MFMA transposed compute (S^T = K Q^T, O^T = V^T P^T).
// KVBLK=64 + LDS double-buffer, single barrier per step; bias rows staged to
// LDS; register-free staging (inverse-swizzle gld_lds); bias in MFMA C-in;
// native exp2 via __builtin_amdgcn_exp2f (r17 fix, verified: flash < gemm0).
// Unchanged this round.
// ---------------------------------------------------------------------------
__global__ __launch_bounds__(256, 3) void flash_mfma(
    const _Float16* __restrict__ Qg, const _Float16* __restrict__ Kg,
    const _Float16* __restrict__ Vtg, const float* __restrict__ relT,
    _Float16* __restrict__ AO) {
  const int nblk = blockIdx.x;
  const int bhl = nblk % 96;                  // same-XCD group key
  const int qt = nblk / 96;                   // 0..7 (128 q rows each)
  const int head = bhl >> 3, b = bhl & 7;
  const int bh = b * NHH + head;
  const int tid = threadIdx.x, w = tid >> 6, lane = tid & 63;
  const int ql = lane & 31;                   // q column within wave tile
  const int hf = lane >> 5;                   // lane half (k/d sub-offset)

  // double-buffered K/V tiles (KVBLK=64): 2 x (8+8) KB = 32 KB
  __shared__ _Float16 Klds[2][64 * 64];       // [row][chunk^key], 8 chunks/row
  __shared__ _Float16 Vlds[2][64 * 64];       // [d-row][chunk^key], 8 chunks/row
  __shared__ __attribute__((aligned(16))) float BiasLds[2][320];  // 5 rows x 63 + pad

  // persistent Q B-frags: B[n=ql][k = s*16 + hf*8 + j]
  const int qglob = qt * 128 + w * 32 + ql;
  const _Float16* Qrow = Qg + ((size_t)bh * NSEQ + qglob) * HD + hf * 8;
  f16x8 bq[4];
#pragma unroll
  for (int s = 0; s < 4; s++) bq[s] = *(const f16x8*)(Qrow + s * 16);

  f32x16 O0 = {}, O1 = {};                    // O^T d-tiles 0..31, 32..63
  float psum = 0.f;

  const _Float16* Kbase = Kg + (size_t)bh * NSEQ * HD;
  const _Float16* Vtbase = Vtg + (size_t)bh * HD * NSEQ;

  // bias: qy fixed per wave; dy = qy - tau + 31, tau = 2*step + t
  const float* relTh = relT + (size_t)head * RELP;
  const int idxb = ql + 31 - 4 * hf;          // dx = idxb - (r&3) - 8*(r>>2)

  // V A-frag row keys (fixed per lane)
  const int vrow0 = ql, vrow1 = 32 + ql;
  const int vkey0 = (vrow0 ^ (vrow0 >> 3)) & 7;
  const int vkey1 = (vrow1 ^ (vrow1 >> 3)) & 7;

  // staging: inverse-swizzled global offsets, linear LDS dest (involution).
  int ks0, ks1, vs0, vs1;
  {
    int c = tid;
    int r = c >> 3, cc = c & 7, key = (r ^ (r >> 3)) & 7;
    ks0 = r * HD + (cc ^ key) * 8;
    vs0 = r * NSEQ + (cc ^ key) * 8;
    c = tid + 256;
    r = c >> 3; cc = c & 7; key = (r ^ (r >> 3)) & 7;
    ks1 = r * HD + (cc ^ key) * 8;
    vs1 = r * NSEQ + (cc ^ key) * 8;
  }

  // stage step s into buffer bsel (K 8KB + V 8KB + bias 316 floats)
  auto stage = [&](int s, int bsel) {
    const _Float16* Ks = Kbase + (size_t)s * 64 * HD;
    const _Float16* Vs = Vtbase + s * 64;
    gld16(Ks + ks0, &Klds[bsel][tid * 8]);
    gld16(Ks + ks1, &Klds[bsel][(tid + 256) * 8]);
    gld16(Vs + vs0, &Vlds[bsel][tid * 8]);
    gld16(Vs + vs1, &Vlds[bsel][(tid + 256) * 8]);
    if (tid < 79) {                           // 79*4 = 316 floats, contiguous
      const int dyLo = qt * 4 + 30 - 2 * s;   // in [0, 58]; span <= RELP pad
      gld16(relTh + dyLo * 63 + tid * 4, &BiasLds[bsel][tid * 4]);
    }
  };

  stage(0, 0);                                // prologue (only exposed latency)

  int cur = 0;
#pragma unroll 2
  for (int s = 0; s < 16; s++) {
    __syncthreads();                          // drains own vmcnt -> buf[cur] ready
    if (s + 1 < 16) stage(s + 1, cur ^ 1);    // in flight under compute(s)

#pragma unroll
    for (int t = 0; t < 2; t++) {
      // bias -> S accumulator (MFMA C-in); reads issue before the MFMA
      // cluster.  p_j of group g needs relT row entry [idxb - 8g - j].
      const float* lb = &BiasLds[cur][(w + 1 - t) * 63 + idxb];
      f32x16 S;
#pragma unroll
      for (int g = 0; g < 4; g++) {
        S[4 * g + 0] = lb[-8 * g - 0];
        S[4 * g + 1] = lb[-8 * g - 1];
        S[4 * g + 2] = lb[-8 * g - 2];
        S[4 * g + 3] = lb[-8 * g - 3];
      }

      // S^T 32x32 tile: A = K rows (t*32+ql), contraction d (64)
      const int arow = t * 32 + ql;
      const int akey = (arow ^ (arow >> 3)) & 7;
      __builtin_amdgcn_s_setprio(1);
#pragma unroll
      for (int ss = 0; ss < 4; ss++) {
        const f16x8 ak = *(const f16x8*)&Klds[cur][((arow << 3) | ((ss * 2 + hf) ^ akey)) * 8];
        S = __builtin_amdgcn_mfma_f32_32x32x16_f16(ak, bq[ss], S, 0, 0, 0);
      }
      __builtin_amdgcn_s_setprio(0);

      // native exp2 (v_exp_f32; log2e folded into Q and relT) + psum + pack
      unsigned int dw[8];
#pragma unroll
      for (int g = 0; g < 4; g++) {
        const float p0 = __builtin_amdgcn_exp2f(S[4 * g + 0]);
        const float p1 = __builtin_amdgcn_exp2f(S[4 * g + 1]);
        const float p2 = __builtin_amdgcn_exp2f(S[4 * g + 2]);
        const float p3 = __builtin_amdgcn_exp2f(S[4 * g + 3]);
        psum += (p0 + p1) + (p2 + p3);
        union { f16x4 h; unsigned int u[2]; } cv;
        cv.h[0] = (_Float16)p0; cv.h[1] = (_Float16)p1;
        cv.h[2] = (_Float16)p2; cv.h[3] = (_Float16)p3;
        dw[2 * g] = cv.u[0]; dw[2 * g + 1] = cv.u[1];
      }

      // PV: B-frag from P^T via half-exchange; A = V^T rows from LDS
      __builtin_amdgcn_s_setprio(1);
#pragma unroll
      for (int s2 = 0; s2 < 2; s2++) {
        const unsigned int x0 = hf ? dw[4 * s2 + 0] : dw[4 * s2 + 2];
        const unsigned int x1 = hf ? dw[4 * s2 + 1] : dw[4 * s2 + 3];
        const unsigned int y0 = (unsigned int)__shfl_xor((int)x0, 32, 64);
        const unsigned int y1 = (unsigned int)__shfl_xor((int)x1, 32, 64);
        union { unsigned int u[4]; f16x8 v; } bp;
        if (hf == 0) {
          bp.u[0] = dw[4 * s2 + 0]; bp.u[1] = dw[4 * s2 + 1];
          bp.u[2] = y0;             bp.u[3] = y1;
        } else {
          bp.u[0] = y0;             bp.u[1] = y1;
          bp.u[2] = dw[4 * s2 + 2]; bp.u[3] = dw[4 * s2 + 3];
        }
        const int kchunk = t * 4 + s2 * 2 + hf;
        const f16x8 av0 = *(const f16x8*)&Vlds[cur][((vrow0 << 3) | (kchunk ^ vkey0)) * 8];
        O0 = __builtin_amdgcn_mfma_f32_32x32x16_f16(av0, bp.v, O0, 0, 0, 0);
        const f16x8 av1 = *(const f16x8*)&Vlds[cur][((vrow1 << 3) | (kchunk ^ vkey1)) * 8];
        O1 = __builtin_amdgcn_mfma_f32_32x32x16_f16(av1, bp.v, O1, 0, 0, 0);
      }
      __builtin_amdgcn_s_setprio(0);
    }
    cur ^= 1;
  }

  // total row-sum for this lane's q column; divide + store O^T
  psum += __shfl_xor(psum, 32, 64);
  const float inv = 1.f / psum;
  _Float16* aoRow = AO + ((size_t)(b * NSEQ + qglob)) * DIMC + head * HD;
#pragma unroll
  for (int g = 0; g < 4; g++) {
    f16x4 o0, o1;
#pragma unroll
    for (int j = 0; j < 4; j++) {
      o0[j] = (_Float16)(O0[4 * g + j] * inv);
      o1[j] = (_Float16)(O1[4 * g + j] * inv);
    }
    const int d0 = 8 * g + 4 * hf;
    *(f16x4*)(aoRow + d0) = o0;
    *(f16x4*)(aoRow + 32 + d0) = o1;
  }
}

extern "C" void kernel_launch(void* const* d_in, const int* in_sizes, int n_in,
                              void* d_out, int out_size, void* d_ws, size_t ws_size,
                              hipStream_t stream) {
  const float* x        = (const float*)d_in[0];
  const float* qkv_w    = (const float*)d_in[1];
  const float* q_bias   = (const float*)d_in[2];
  const float* v_bias   = (const float*)d_in[3];
  const float* proj_w   = (const float*)d_in[4];
  const float* proj_b   = (const float*)d_in[5];
  const float* rel_tab  = (const float*)d_in[6];
  float* out = (float*)d_out;

  const size_t NTOK = (size_t)8 * NHH * NSEQ * HD;
  _Float16* Xb     = (_Float16*)d_ws;
  _Float16* Wqkvb  = Xb + SX;
  _Float16* Wprojb = Wqkvb + SW1;
  _Float16* Qb     = Wprojb + SW2;
  _Float16* Kb     = Qb + NTOK;
  _Float16* Vt     = Kb + NTOK;             // V written transposed by qkv gemm
  float*    relT   = (float*)(Vt + NTOK);   // 12*4032 fp32 = 193 KB
  _Float16* AOb    = Xb;                    // alias: x consumed before flash writes

  cast_f16<<<dim3(NCAST + NRELB), 256, 0, stream>>>(x, qkv_w, proj_w, Xb,
                                                    rel_tab, relT);

  gemm_mfma<0><<<dim3(64 * 36), 256, 0, stream>>>(
      Xb, Wqkvb, q_bias, v_bias, nullptr, Qb, Kb, Vt);

  flash_mfma<<<dim3(768), 256, 0, stream>>>(Qb, Kb, Vt, relT, AOb);

  gemm_mfma<1><<<dim3(64 * 12), 256, 0, stream>>>(
      AOb, Wprojb, proj_b, nullptr, out, nullptr, nullptr, nullptr);
}

// Round 13
// 188.761 us; speedup vs baseline: 1.1089x; 1.0248x over previous
//
#include <hip/hip_runtime.h>
#include <cstdint>
#include <cstddef>

#define DIMC 768
#define NHH  12
#define NSEQ 1024
#define HD   64

#define SX  6291456   // x elems (8*1024*768)
#define SW1 1769472   // qkv_w elems
#define SW2 589824    // proj_w elems

#define RELN 3969     // 63*63 table entries per head
#define RELP 4032     // padded stride

#define NCAST ((SX + SW1 + SW2) / 2048)       // 4224 cast blocks
#define NRELB ((NHH * RELN + 255) / 256)      // 187 relt blocks

#define LOG2E 1.4426950408889634f

typedef _Float16 f16x8 __attribute__((ext_vector_type(8)));
typedef _Float16 f16x4 __attribute__((ext_vector_type(4)));
typedef __fp16   h16x2 __attribute__((ext_vector_type(2)));   // intrinsic-facing pair type
typedef float    f32x4 __attribute__((ext_vector_type(4)));
typedef float    f32x16 __attribute__((ext_vector_type(16)));

__device__ inline void gld16(const void* g, void* l) {
  __builtin_amdgcn_global_load_lds(
      (const __attribute__((address_space(1))) void*)g,
      (__attribute__((address_space(3))) void*)l, 16, 0, 0);
}

// ---------------------------------------------------------------------------
// Fused fp32 -> fp16 cast of x | qkv_w | proj_w into one contiguous ws region,
// PLUS (tail blocks) the head-major relative-bias transpose.  relT is
// pre-scaled by log2e so flash can use native exp2 (v_exp_f32) with no
// per-element multiply; the matching log2e factor on S goes into the Q scale.
// ---------------------------------------------------------------------------
__global__ __launch_bounds__(256) void cast_f16(
    const float* __restrict__ x, const float* __restrict__ w1,
    const float* __restrict__ w2, _Float16* __restrict__ dst,
    const float* __restrict__ rel_table, float* __restrict__ relT) {
  if (blockIdx.x >= NCAST) {                  // relT transpose tail
    const int g = (blockIdx.x - NCAST) * 256 + threadIdx.x;
    if (g < NHH * RELN) {
      const int h = g / RELN, idx = g - h * RELN;
      relT[h * RELP + idx] = rel_table[idx * NHH + h] * LOG2E;
    }
    return;
  }
  const long long t = (long long)blockIdx.x * 256 + threadIdx.x;
  const long long i = t * 8;
  const float* src; long long off;
  if (i < SX) { src = x; off = i; }
  else if (i < SX + SW1) { src = w1; off = i - SX; }
  else { src = w2; off = i - (SX + SW1); }
  const float4 a = *(const float4*)(src + off);
  const float4 b = *(const float4*)(src + off + 4);
  f16x8 o;
  o[0] = (_Float16)a.x; o[1] = (_Float16)a.y; o[2] = (_Float16)a.z; o[3] = (_Float16)a.w;
  o[4] = (_Float16)b.x; o[5] = (_Float16)b.y; o[6] = (_Float16)b.z; o[7] = (_Float16)b.w;
  *(f16x8*)(dst + i) = o;
}

// ---------------------------------------------------------------------------
// MFMA GEMM: C[m,o] = sum_k A[m,k]*W[o,k].  128x64 tiles (r11 win: occupancy
// 15->35%, 55.3->46.0us).  Single buffer, two barriers, compiler-scheduled;
// T2 8-chunk involution swizzle (conflicts 0); BK=64; acc[2][4]; LDS 24KB.
// XCD swizzle: blockIdx%8 = m%8 -> A-panels XCD-local.  Unchanged this round.
// EPI==0: scatter f16 Q(+bias, *0.125*log2e), K, V->Vt transposed.
// EPI==1: fp32 outF = acc + b0[o].
// ---------------------------------------------------------------------------
template <int EPI>
__global__ __launch_bounds__(256) void gemm_mfma(
    const _Float16* __restrict__ A, const _Float16* __restrict__ W,
    const float* __restrict__ b0, const float* __restrict__ b1,
    float* __restrict__ outF, _Float16* __restrict__ oq,
    _Float16* __restrict__ ok, _Float16* __restrict__ ovt) {
  __shared__ _Float16 Alds[128 * 64];
  __shared__ _Float16 Blds[64 * 64];

  const int tid = threadIdx.x;
  const int w = tid >> 6, lane = tid & 63, quad = lane >> 4, l16 = lane & 15;
  const int m0 = (blockIdx.x & 63) << 7;
  const int o0 = (blockIdx.x >> 6) << 6;      // 64-wide o-panel
  const int wr = w * 32;                      // wave owns 32 rows x 64 cols
  const int rkey = l16 & 7;                   // read-side swizzle key

  f32x4 acc[2][4];
#pragma unroll
  for (int i = 0; i < 2; i++)
#pragma unroll
    for (int j = 0; j < 4; j++) acc[i][j] = (f32x4){0.f, 0.f, 0.f, 0.f};

  // staging: A slots tid+k*256 (k=0..3) -> row=(tid>>3)+32k, chunk=tid&7;
  //          B slots tid+k*256 (k=0..1).  Source chunk = (tid&7) ^ (row&7);
  //          row&7 == (tid>>3)&7 for all k (invariant key).
  const int srow = tid >> 3;
  const int sch = ((tid & 7) ^ (srow & 7)) * 8;
  const _Float16* Ap = A + (size_t)(m0 + srow) * DIMC + sch;
  const _Float16* Wp = W + (size_t)(o0 + srow) * DIMC + sch;
  _Float16* Adst = &Alds[tid * 8];
  _Float16* Bdst = &Blds[tid * 8];

  for (int k0 = 0; k0 < DIMC; k0 += 64) {
    __syncthreads();
#pragma unroll
    for (int k = 0; k < 4; k++)
      gld16(Ap + k0 + k * 32 * DIMC, Adst + k * 2048);
#pragma unroll
    for (int k = 0; k < 2; k++)
      gld16(Wp + k0 + k * 32 * DIMC, Bdst + k * 2048);
    __syncthreads();                          // vmcnt drained -> tile visible

#pragma unroll
    for (int ks = 0; ks < 2; ks++) {
      const int ch = (((ks << 2) + quad) ^ rkey) * 8;
      f16x8 a[2], b[4];
#pragma unroll
      for (int i = 0; i < 2; i++)
        a[i] = *(const f16x8*)&Alds[(wr + i * 16 + l16) * 64 + ch];
#pragma unroll
      for (int j = 0; j < 4; j++)
        b[j] = *(const f16x8*)&Blds[(j * 16 + l16) * 64 + ch];
#pragma unroll
      for (int i = 0; i < 2; i++)
#pragma unroll
        for (int j = 0; j < 4; j++)
          acc[i][j] = __builtin_amdgcn_mfma_f32_16x16x32_f16(a[i], b[j], acc[i][j], 0, 0, 0);
    }
  }

  if constexpr (EPI == 0) {
#pragma unroll
    for (int j = 0; j < 4; j++) {
      const int o = o0 + j * 16 + l16;
      const int part = o / DIMC;
      const int cc = o - part * DIMC;
      const int hh = cc >> 6, d = cc & 63;
      const float badd = (part == 0) ? b0[cc] : (part == 2 ? b1[cc] : 0.f);
      if (part == 2) {
        // V: write transposed into Vt[bh][d][n], f16x4 along n
#pragma unroll
        for (int i = 0; i < 2; i++) {
          const int mb = m0 + wr + i * 16 + quad * 4;
          const int bb = mb >> 10, n0 = mb & 1023;
          f16x4 vv;
#pragma unroll
          for (int r = 0; r < 4; r++) vv[r] = (_Float16)(acc[i][j][r] + badd);
          *(f16x4*)(ovt + (((size_t)(bb * NHH + hh)) * HD + d) * NSEQ + n0) = vv;
        }
      } else {
        _Float16* dst = (part == 0) ? oq : ok;
#pragma unroll
        for (int i = 0; i < 2; i++) {
#pragma unroll
          for (int r = 0; r < 4; r++) {
            const int m = m0 + wr + i * 16 + quad * 4 + r;
            const int bb = m >> 10, n = m & 1023;
            float v = acc[i][j][r];
            if (part == 0) v = (v + badd) * (0.125f * LOG2E);
            dst[(((size_t)(bb * NHH + hh)) * NSEQ + n) * HD + d] = (_Float16)v;
          }
        }
      }
    }
  } else {
#pragma unroll
    for (int j = 0; j < 4; j++) {
      const int o = o0 + j * 16 + l16;
      const float bo = b0[o];
#pragma unroll
      for (int i = 0; i < 2; i++) {
#pragma unroll
        for (int r = 0; r < 4; r++) {
          const int m = m0 + wr + i * 16 + quad * 4 + r;
          outF[(size_t)m * DIMC + o] = acc[i][j][r] + bo;
        }
      }
    }
  }
}

// ---------------------------------------------------------------------------
// Flash attention, 32x32x16 MFMA transposed compute (S^T = K Q^T, O^T = V^T P^T).
// KVBLK=64 + LDS double-buffer, single barrier per step; bias rows staged to
// LDS; register-free staging (inverse-swizzle gld_lds); bias in MFMA C-in;
// native exp2 via __builtin_amdgcn_exp2f.
// Round 20 = round 19 with the intrinsic TYPE fix (cvt_pkrtz/fdot2 take
// __fp16-based ext vectors, not _Float16-based; bit layout identical):
//  * v_cvt_pkrtz_f16_f32: one op packs 2 floats -> dword (was 2 cvt + pack).
//  * v_dot2_f32_f16 (fdot2) with (1,1): psum accumulates each packed pair in
//    one op, AND psum now sums the same f16-rounded values the PV numerator
//    uses (consistent ratio rounding).
//  Net ~ -24 VALU per t-tile of ~56.
// ---------------------------------------------------------------------------
__global__ __launch_bounds__(256, 3) void flash_mfma(
    const _Float16* __restrict__ Qg, const _Float16* __restrict__ Kg,
    const _Float16* __restrict__ Vtg, const float* __restrict__ relT,
    _Float16* __restrict__ AO) {
  const int nblk = blockIdx.x;
  const int bhl = nblk % 96;                  // same-XCD group key
  const int qt = nblk / 96;                   // 0..7 (128 q rows each)
  const int head = bhl >> 3, b = bhl & 7;
  const int bh = b * NHH + head;
  const int tid = threadIdx.x, w = tid >> 6, lane = tid & 63;
  const int ql = lane & 31;                   // q column within wave tile
  const int hf = lane >> 5;                   // lane half (k/d sub-offset)

  // double-buffered K/V tiles (KVBLK=64): 2 x (8+8) KB = 32 KB
  __shared__ _Float16 Klds[2][64 * 64];       // [row][chunk^key], 8 chunks/row
  __shared__ _Float16 Vlds[2][64 * 64];       // [d-row][chunk^key], 8 chunks/row
  __shared__ __attribute__((aligned(16))) float BiasLds[2][320];  // 5 rows x 63 + pad

  // persistent Q B-frags: B[n=ql][k = s*16 + hf*8 + j]
  const int qglob = qt * 128 + w * 32 + ql;
  const _Float16* Qrow = Qg + ((size_t)bh * NSEQ + qglob) * HD + hf * 8;
  f16x8 bq[4];
#pragma unroll
  for (int s = 0; s < 4; s++) bq[s] = *(const f16x8*)(Qrow + s * 16);

  f32x16 O0 = {}, O1 = {};                    // O^T d-tiles 0..31, 32..63
  float psum = 0.f;
  const h16x2 one2 = {(__fp16)1.f, (__fp16)1.f};

  const _Float16* Kbase = Kg + (size_t)bh * NSEQ * HD;
  const _Float16* Vtbase = Vtg + (size_t)bh * HD * NSEQ;

  // bias: qy fixed per wave; dy = qy - tau + 31, tau = 2*step + t
  const float* relTh = relT + (size_t)head * RELP;
  const int idxb = ql + 31 - 4 * hf;          // dx = idxb - (r&3) - 8*(r>>2)

  // V A-frag row keys (fixed per lane)
  const int vrow0 = ql, vrow1 = 32 + ql;
  const int vkey0 = (vrow0 ^ (vrow0 >> 3)) & 7;
  const int vkey1 = (vrow1 ^ (vrow1 >> 3)) & 7;

  // staging: inverse-swizzled global offsets, linear LDS dest (involution).
  int ks0, ks1, vs0, vs1;
  {
    int c = tid;
    int r = c >> 3, cc = c & 7, key = (r ^ (r >> 3)) & 7;
    ks0 = r * HD + (cc ^ key) * 8;
    vs0 = r * NSEQ + (cc ^ key) * 8;
    c = tid + 256;
    r = c >> 3; cc = c & 7; key = (r ^ (r >> 3)) & 7;
    ks1 = r * HD + (cc ^ key) * 8;
    vs1 = r * NSEQ + (cc ^ key) * 8;
  }

  // stage step s into buffer bsel (K 8KB + V 8KB + bias 316 floats)
  auto stage = [&](int s, int bsel) {
    const _Float16* Ks = Kbase + (size_t)s * 64 * HD;
    const _Float16* Vs = Vtbase + s * 64;
    gld16(Ks + ks0, &Klds[bsel][tid * 8]);
    gld16(Ks + ks1, &Klds[bsel][(tid + 256) * 8]);
    gld16(Vs + vs0, &Vlds[bsel][tid * 8]);
    gld16(Vs + vs1, &Vlds[bsel][(tid + 256) * 8]);
    if (tid < 79) {                           // 79*4 = 316 floats, contiguous
      const int dyLo = qt * 4 + 30 - 2 * s;   // in [0, 58]; span <= RELP pad
      gld16(relTh + dyLo * 63 + tid * 4, &BiasLds[bsel][tid * 4]);
    }
  };

  stage(0, 0);                                // prologue (only exposed latency)

  int cur = 0;
#pragma unroll 2
  for (int s = 0; s < 16; s++) {
    __syncthreads();                          // drains own vmcnt -> buf[cur] ready
    if (s + 1 < 16) stage(s + 1, cur ^ 1);    // in flight under compute(s)

#pragma unroll
    for (int t = 0; t < 2; t++) {
      // bias -> S accumulator (MFMA C-in); reads issue before the MFMA
      // cluster.  p_j of group g needs relT row entry [idxb - 8g - j].
      const float* lb = &BiasLds[cur][(w + 1 - t) * 63 + idxb];
      f32x16 S;
#pragma unroll
      for (int g = 0; g < 4; g++) {
        S[4 * g + 0] = lb[-8 * g - 0];
        S[4 * g + 1] = lb[-8 * g - 1];
        S[4 * g + 2] = lb[-8 * g - 2];
        S[4 * g + 3] = lb[-8 * g - 3];
      }

      // S^T 32x32 tile: A = K rows (t*32+ql), contraction d (64)
      const int arow = t * 32 + ql;
      const int akey = (arow ^ (arow >> 3)) & 7;
      __builtin_amdgcn_s_setprio(1);
#pragma unroll
      for (int ss = 0; ss < 4; ss++) {
        const f16x8 ak = *(const f16x8*)&Klds[cur][((arow << 3) | ((ss * 2 + hf) ^ akey)) * 8];
        S = __builtin_amdgcn_mfma_f32_32x32x16_f16(ak, bq[ss], S, 0, 0, 0);
      }
      __builtin_amdgcn_s_setprio(0);

      // native exp2 -> pack pairs (v_cvt_pkrtz) -> psum via v_dot2_f32_f16
      unsigned int dw[8];
#pragma unroll
      for (int g = 0; g < 4; g++) {
        const float p0 = __builtin_amdgcn_exp2f(S[4 * g + 0]);
        const float p1 = __builtin_amdgcn_exp2f(S[4 * g + 1]);
        const float p2 = __builtin_amdgcn_exp2f(S[4 * g + 2]);
        const float p3 = __builtin_amdgcn_exp2f(S[4 * g + 3]);
        const h16x2 h01 = __builtin_amdgcn_cvt_pkrtz(p0, p1);
        const h16x2 h23 = __builtin_amdgcn_cvt_pkrtz(p2, p3);
        psum = __builtin_amdgcn_fdot2(h01, one2, psum, false);
        psum = __builtin_amdgcn_fdot2(h23, one2, psum, false);
        union { h16x2 h; unsigned int u; } c0, c1;
        c0.h = h01; c1.h = h23;
        dw[2 * g] = c0.u; dw[2 * g + 1] = c1.u;
      }

      // PV: B-frag from P^T via half-exchange; A = V^T rows from LDS
      __builtin_amdgcn_s_setprio(1);
#pragma unroll
      for (int s2 = 0; s2 < 2; s2++) {
        const unsigned int x0 = hf ? dw[4 * s2 + 0] : dw[4 * s2 + 2];
        const unsigned int x1 = hf ? dw[4 * s2 + 1] : dw[4 * s2 + 3];
        const unsigned int y0 = (unsigned int)__shfl_xor((int)x0, 32, 64);
        const unsigned int y1 = (unsigned int)__shfl_xor((int)x1, 32, 64);
        union { unsigned int u[4]; f16x8 v; } bp;
        if (hf == 0) {
          bp.u[0] = dw[4 * s2 + 0]; bp.u[1] = dw[4 * s2 + 1];
          bp.u[2] = y0;             bp.u[3] = y1;
        } else {
          bp.u[0] = y0;             bp.u[1] = y1;
          bp.u[2] = dw[4 * s2 + 2]; bp.u[3] = dw[4 * s2 + 3];
        }
        const int kchunk = t * 4 + s2 * 2 + hf;
        const f16x8 av0 = *(const f16x8*)&Vlds[cur][((vrow0 << 3) | (kchunk ^ vkey0)) * 8];
        O0 = __builtin_amdgcn_mfma_f32_32x32x16_f16(av0, bp.v, O0, 0, 0, 0);
        const f16x8 av1 = *(const f16x8*)&Vlds[cur][((vrow1 << 3) | (kchunk ^ vkey1)) * 8];
        O1 = __builtin_amdgcn_mfma_f32_32x32x16_f16(av1, bp.v, O1, 0, 0, 0);
      }
      __builtin_amdgcn_s_setprio(0);
    }
    cur ^= 1;
  }

  // total row-sum for this lane's q column; divide + store O^T
  psum += __shfl_xor(psum, 32, 64);
  const float inv = 1.f / psum;
  _Float16* aoRow = AO + ((size_t)(b * NSEQ + qglob)) * DIMC + head * HD;
#pragma unroll
  for (int g = 0; g < 4; g++) {
    f16x4 o0, o1;
#pragma unroll
    for (int j = 0; j < 4; j++) {
      o0[j] = (_Float16)(O0[4 * g + j] * inv);
      o1[j] = (_Float16)(O1[4 * g + j] * inv);
    }
    const int d0 = 8 * g + 4 * hf;
    *(f16x4*)(aoRow + d0) = o0;
    *(f16x4*)(aoRow + 32 + d0) = o1;
  }
}

extern "C" void kernel_launch(void* const* d_in, const int* in_sizes, int n_in,
                              void* d_out, int out_size, void* d_ws, size_t ws_size,
                              hipStream_t stream) {
  const float* x        = (const float*)d_in[0];
  const float* qkv_w    = (const float*)d_in[1];
  const float* q_bias   = (const float*)d_in[2];
  const float* v_bias   = (const float*)d_in[3];
  const float* proj_w   = (const float*)d_in[4];
  const float* proj_b   = (const float*)d_in[5];
  const float* rel_tab  = (const float*)d_in[6];
  float* out = (float*)d_out;

  const size_t NTOK = (size_t)8 * NHH * NSEQ * HD;
  _Float16* Xb     = (_Float16*)d_ws;
  _Float16* Wqkvb  = Xb + SX;
  _Float16* Wprojb = Wqkvb + SW1;
  _Float16* Qb     = Wprojb + SW2;
  _Float16* Kb     = Qb + NTOK;
  _Float16* Vt     = Kb + NTOK;             // V written transposed by qkv gemm
  float*    relT   = (float*)(Vt + NTOK);   // 12*4032 fp32 = 193 KB
  _Float16* AOb    = Xb;                    // alias: x consumed before flash writes

  cast_f16<<<dim3(NCAST + NRELB), 256, 0, stream>>>(x, qkv_w, proj_w, Xb,
                                                    rel_tab, relT);

  gemm_mfma<0><<<dim3(64 * 36), 256, 0, stream>>>(
      Xb, Wqkvb, q_bias, v_bias, nullptr, Qb, Kb, Vt);

  flash_mfma<<<dim3(768), 256, 0, stream>>>(Qb, Kb, Vt, relT, AOb);

  gemm_mfma<1><<<dim3(64 * 12), 256, 0, stream>>>(
      AOb, Wprojb, proj_b, nullptr, out, nullptr, nullptr, nullptr);
}

// Round 14
// 188.716 us; speedup vs baseline: 1.1092x; 1.0002x over previous
//
#include <hip/hip_runtime.h>
#include <cstdint>
#include <cstddef>

#define DIMC 768
#define NHH  12
#define NSEQ 1024
#define HD   64

#define SX  6291456   // x elems (8*1024*768)
#define SW1 1769472   // qkv_w elems
#define SW2 589824    // proj_w elems

#define RELN 3969     // 63*63 table entries per head
#define RELP 4032     // padded stride

#define NCAST ((SX + SW1 + SW2) / 2048)       // 4224 cast blocks
#define NRELB ((NHH * RELN + 255) / 256)      // 187 relt blocks

#define LOG2E 1.4426950408889634f

typedef _Float16 f16x8 __attribute__((ext_vector_type(8)));
typedef _Float16 f16x4 __attribute__((ext_vector_type(4)));
typedef __fp16   h16x2 __attribute__((ext_vector_type(2)));   // intrinsic-facing pair type
typedef float    f32x4 __attribute__((ext_vector_type(4)));
typedef float    f32x16 __attribute__((ext_vector_type(16)));

__device__ inline void gld16(const void* g, void* l) {
  __builtin_amdgcn_global_load_lds(
      (const __attribute__((address_space(1))) void*)g,
      (__attribute__((address_space(3))) void*)l, 16, 0, 0);
}

// ---------------------------------------------------------------------------
// Fused fp32 -> fp16 cast of x | qkv_w | proj_w into one contiguous ws region,
// PLUS (tail blocks) the head-major relative-bias transpose.  relT is
// pre-scaled by log2e so flash can use native exp2 (v_exp_f32) with no
// per-element multiply; the matching log2e factor on S goes into the Q scale.
// ---------------------------------------------------------------------------
__global__ __launch_bounds__(256) void cast_f16(
    const float* __restrict__ x, const float* __restrict__ w1,
    const float* __restrict__ w2, _Float16* __restrict__ dst,
    const float* __restrict__ rel_table, float* __restrict__ relT) {
  if (blockIdx.x >= NCAST) {                  // relT transpose tail
    const int g = (blockIdx.x - NCAST) * 256 + threadIdx.x;
    if (g < NHH * RELN) {
      const int h = g / RELN, idx = g - h * RELN;
      relT[h * RELP + idx] = rel_table[idx * NHH + h] * LOG2E;
    }
    return;
  }
  const long long t = (long long)blockIdx.x * 256 + threadIdx.x;
  const long long i = t * 8;
  const float* src; long long off;
  if (i < SX) { src = x; off = i; }
  else if (i < SX + SW1) { src = w1; off = i - SX; }
  else { src = w2; off = i - (SX + SW1); }
  const float4 a = *(const float4*)(src + off);
  const float4 b = *(const float4*)(src + off + 4);
  f16x8 o;
  o[0] = (_Float16)a.x; o[1] = (_Float16)a.y; o[2] = (_Float16)a.z; o[3] = (_Float16)a.w;
  o[4] = (_Float16)b.x; o[5] = (_Float16)b.y; o[6] = (_Float16)b.z; o[7] = (_Float16)b.w;
  *(f16x8*)(dst + i) = o;
}

// ---------------------------------------------------------------------------
// MFMA GEMM: C[m,o] = sum_k A[m,k]*W[o,k].  128x64 tiles (r11 win: occupancy
// 15->35%, 55.3->46.0us).  Single buffer, two barriers, compiler-scheduled;
// T2 8-chunk involution swizzle (conflicts 0); BK=64; acc[2][4]; LDS 24KB.
// XCD swizzle: blockIdx%8 = m%8 -> A-panels XCD-local.  Unchanged this round.
// EPI==0: scatter f16 Q(+bias, *0.125*log2e), K, V->Vt transposed.
// EPI==1: fp32 outF = acc + b0[o].
// ---------------------------------------------------------------------------
template <int EPI>
__global__ __launch_bounds__(256) void gemm_mfma(
    const _Float16* __restrict__ A, const _Float16* __restrict__ W,
    const float* __restrict__ b0, const float* __restrict__ b1,
    float* __restrict__ outF, _Float16* __restrict__ oq,
    _Float16* __restrict__ ok, _Float16* __restrict__ ovt) {
  __shared__ _Float16 Alds[128 * 64];
  __shared__ _Float16 Blds[64 * 64];

  const int tid = threadIdx.x;
  const int w = tid >> 6, lane = tid & 63, quad = lane >> 4, l16 = lane & 15;
  const int m0 = (blockIdx.x & 63) << 7;
  const int o0 = (blockIdx.x >> 6) << 6;      // 64-wide o-panel
  const int wr = w * 32;                      // wave owns 32 rows x 64 cols
  const int rkey = l16 & 7;                   // read-side swizzle key

  f32x4 acc[2][4];
#pragma unroll
  for (int i = 0; i < 2; i++)
#pragma unroll
    for (int j = 0; j < 4; j++) acc[i][j] = (f32x4){0.f, 0.f, 0.f, 0.f};

  // staging: A slots tid+k*256 (k=0..3) -> row=(tid>>3)+32k, chunk=tid&7;
  //          B slots tid+k*256 (k=0..1).  Source chunk = (tid&7) ^ (row&7);
  //          row&7 == (tid>>3)&7 for all k (invariant key).
  const int srow = tid >> 3;
  const int sch = ((tid & 7) ^ (srow & 7)) * 8;
  const _Float16* Ap = A + (size_t)(m0 + srow) * DIMC + sch;
  const _Float16* Wp = W + (size_t)(o0 + srow) * DIMC + sch;
  _Float16* Adst = &Alds[tid * 8];
  _Float16* Bdst = &Blds[tid * 8];

  for (int k0 = 0; k0 < DIMC; k0 += 64) {
    __syncthreads();
#pragma unroll
    for (int k = 0; k < 4; k++)
      gld16(Ap + k0 + k * 32 * DIMC, Adst + k * 2048);
#pragma unroll
    for (int k = 0; k < 2; k++)
      gld16(Wp + k0 + k * 32 * DIMC, Bdst + k * 2048);
    __syncthreads();                          // vmcnt drained -> tile visible

#pragma unroll
    for (int ks = 0; ks < 2; ks++) {
      const int ch = (((ks << 2) + quad) ^ rkey) * 8;
      f16x8 a[2], b[4];
#pragma unroll
      for (int i = 0; i < 2; i++)
        a[i] = *(const f16x8*)&Alds[(wr + i * 16 + l16) * 64 + ch];
#pragma unroll
      for (int j = 0; j < 4; j++)
        b[j] = *(const f16x8*)&Blds[(j * 16 + l16) * 64 + ch];
#pragma unroll
      for (int i = 0; i < 2; i++)
#pragma unroll
        for (int j = 0; j < 4; j++)
          acc[i][j] = __builtin_amdgcn_mfma_f32_16x16x32_f16(a[i], b[j], acc[i][j], 0, 0, 0);
    }
  }

  if constexpr (EPI == 0) {
#pragma unroll
    for (int j = 0; j < 4; j++) {
      const int o = o0 + j * 16 + l16;
      const int part = o / DIMC;
      const int cc = o - part * DIMC;
      const int hh = cc >> 6, d = cc & 63;
      const float badd = (part == 0) ? b0[cc] : (part == 2 ? b1[cc] : 0.f);
      if (part == 2) {
        // V: write transposed into Vt[bh][d][n], f16x4 along n
#pragma unroll
        for (int i = 0; i < 2; i++) {
          const int mb = m0 + wr + i * 16 + quad * 4;
          const int bb = mb >> 10, n0 = mb & 1023;
          f16x4 vv;
#pragma unroll
          for (int r = 0; r < 4; r++) vv[r] = (_Float16)(acc[i][j][r] + badd);
          *(f16x4*)(ovt + (((size_t)(bb * NHH + hh)) * HD + d) * NSEQ + n0) = vv;
        }
      } else {
        _Float16* dst = (part == 0) ? oq : ok;
#pragma unroll
        for (int i = 0; i < 2; i++) {
#pragma unroll
          for (int r = 0; r < 4; r++) {
            const int m = m0 + wr + i * 16 + quad * 4 + r;
            const int bb = m >> 10, n = m & 1023;
            float v = acc[i][j][r];
            if (part == 0) v = (v + badd) * (0.125f * LOG2E);
            dst[(((size_t)(bb * NHH + hh)) * NSEQ + n) * HD + d] = (_Float16)v;
          }
        }
      }
    }
  } else {
#pragma unroll
    for (int j = 0; j < 4; j++) {
      const int o = o0 + j * 16 + l16;
      const float bo = b0[o];
#pragma unroll
      for (int i = 0; i < 2; i++) {
#pragma unroll
        for (int r = 0; r < 4; r++) {
          const int m = m0 + wr + i * 16 + quad * 4 + r;
          outF[(size_t)m * DIMC + o] = acc[i][j][r] + bo;
        }
      }
    }
  }
}

// ---------------------------------------------------------------------------
// Flash attention, 32x32x16 MFMA transposed compute (S^T = K Q^T, O^T = V^T P^T).
// KVBLK=64 + LDS double-buffer, single barrier per step; bias rows staged to
// LDS; register-free staging (inverse-swizzle gld_lds); bias in MFMA C-in;
// native exp2; pkrtz pack + fdot2 psum (r13, verified).
// Round 21: intra-wave t-tile pipeline (T15 family; +7-11% on attn in m214).
// Old order S0->sm0->PV0->S1->sm1->PV1 serializes MFMA and VALU phases inside
// a wave; with only 3 waves/SIMD (grid-capped 768=3/CU) the pipes idle.
// New order: S0,S1 MFMAs back-to-back -> sm0 (covers S1 latency) -> PV0 ->
// sm1 (VALU issues under PV0 execution; separate pipes) -> PV1.
// Cost: S1 live +16 VGPR (~100 total, budget 170 at 3 waves/SIMD).
// ---------------------------------------------------------------------------
__global__ __launch_bounds__(256, 3) void flash_mfma(
    const _Float16* __restrict__ Qg, const _Float16* __restrict__ Kg,
    const _Float16* __restrict__ Vtg, const float* __restrict__ relT,
    _Float16* __restrict__ AO) {
  const int nblk = blockIdx.x;
  const int bhl = nblk % 96;                  // same-XCD group key
  const int qt = nblk / 96;                   // 0..7 (128 q rows each)
  const int head = bhl >> 3, b = bhl & 7;
  const int bh = b * NHH + head;
  const int tid = threadIdx.x, w = tid >> 6, lane = tid & 63;
  const int ql = lane & 31;                   // q column within wave tile
  const int hf = lane >> 5;                   // lane half (k/d sub-offset)

  // double-buffered K/V tiles (KVBLK=64): 2 x (8+8) KB = 32 KB
  __shared__ _Float16 Klds[2][64 * 64];       // [row][chunk^key], 8 chunks/row
  __shared__ _Float16 Vlds[2][64 * 64];       // [d-row][chunk^key], 8 chunks/row
  __shared__ __attribute__((aligned(16))) float BiasLds[2][320];  // 5 rows x 63 + pad

  // persistent Q B-frags: B[n=ql][k = s*16 + hf*8 + j]
  const int qglob = qt * 128 + w * 32 + ql;
  const _Float16* Qrow = Qg + ((size_t)bh * NSEQ + qglob) * HD + hf * 8;
  f16x8 bq[4];
#pragma unroll
  for (int s = 0; s < 4; s++) bq[s] = *(const f16x8*)(Qrow + s * 16);

  f32x16 O0 = {}, O1 = {};                    // O^T d-tiles 0..31, 32..63
  float psum = 0.f;
  const h16x2 one2 = {(__fp16)1.f, (__fp16)1.f};

  const _Float16* Kbase = Kg + (size_t)bh * NSEQ * HD;
  const _Float16* Vtbase = Vtg + (size_t)bh * HD * NSEQ;

  // bias: qy fixed per wave; dy = qy - tau + 31, tau = 2*step + t
  const float* relTh = relT + (size_t)head * RELP;
  const int idxb = ql + 31 - 4 * hf;          // dx = idxb - (r&3) - 8*(r>>2)

  // V A-frag row keys (fixed per lane)
  const int vrow0 = ql, vrow1 = 32 + ql;
  const int vkey0 = (vrow0 ^ (vrow0 >> 3)) & 7;
  const int vkey1 = (vrow1 ^ (vrow1 >> 3)) & 7;

  // S^T A-operand row keys for the two t-tiles (fixed per lane)
  const int arow0 = ql,      akey0 = (arow0 ^ (arow0 >> 3)) & 7;
  const int arow1 = 32 + ql, akey1 = (arow1 ^ (arow1 >> 3)) & 7;

  // staging: inverse-swizzled global offsets, linear LDS dest (involution).
  int ks0, ks1, vs0, vs1;
  {
    int c = tid;
    int r = c >> 3, cc = c & 7, key = (r ^ (r >> 3)) & 7;
    ks0 = r * HD + (cc ^ key) * 8;
    vs0 = r * NSEQ + (cc ^ key) * 8;
    c = tid + 256;
    r = c >> 3; cc = c & 7; key = (r ^ (r >> 3)) & 7;
    ks1 = r * HD + (cc ^ key) * 8;
    vs1 = r * NSEQ + (cc ^ key) * 8;
  }

  // stage step s into buffer bsel (K 8KB + V 8KB + bias 316 floats)
  auto stage = [&](int s, int bsel) {
    const _Float16* Ks = Kbase + (size_t)s * 64 * HD;
    const _Float16* Vs = Vtbase + s * 64;
    gld16(Ks + ks0, &Klds[bsel][tid * 8]);
    gld16(Ks + ks1, &Klds[bsel][(tid + 256) * 8]);
    gld16(Vs + vs0, &Vlds[bsel][tid * 8]);
    gld16(Vs + vs1, &Vlds[bsel][(tid + 256) * 8]);
    if (tid < 79) {                           // 79*4 = 316 floats, contiguous
      const int dyLo = qt * 4 + 30 - 2 * s;   // in [0, 58]; span <= RELP pad
      gld16(relTh + dyLo * 63 + tid * 4, &BiasLds[bsel][tid * 4]);
    }
  };

// softmax (exp2 + pkrtz + fdot2) for one S tile -> dw[4]
#define SOFTMAX(SV, DW)                                           \
  {                                                               \
    _Pragma("unroll") for (int g = 0; g < 4; g++) {               \
      const float p0 = __builtin_amdgcn_exp2f(SV[4 * g + 0]);     \
      const float p1 = __builtin_amdgcn_exp2f(SV[4 * g + 1]);     \
      const float p2 = __builtin_amdgcn_exp2f(SV[4 * g + 2]);     \
      const float p3 = __builtin_amdgcn_exp2f(SV[4 * g + 3]);     \
      const h16x2 h01 = __builtin_amdgcn_cvt_pkrtz(p0, p1);       \
      const h16x2 h23 = __builtin_amdgcn_cvt_pkrtz(p2, p3);       \
      psum = __builtin_amdgcn_fdot2(h01, one2, psum, false);      \
      psum = __builtin_amdgcn_fdot2(h23, one2, psum, false);      \
      union { h16x2 h; unsigned int u; } c0, c1;                  \
      c0.h = h01; c1.h = h23;                                     \
      DW[2 * g] = c0.u; DW[2 * g + 1] = c1.u;                     \
    }                                                             \
  }

// PV for one t tile: B-frag from P^T via half-exchange; A = V^T rows
#define PVACC(DW, T)                                                          \
  {                                                                           \
    _Pragma("unroll") for (int s2 = 0; s2 < 2; s2++) {                        \
      const unsigned int x0 = hf ? DW[4 * s2 + 0] : DW[4 * s2 + 2];           \
      const unsigned int x1 = hf ? DW[4 * s2 + 1] : DW[4 * s2 + 3];           \
      const unsigned int y0 = (unsigned int)__shfl_xor((int)x0, 32, 64);      \
      const unsigned int y1 = (unsigned int)__shfl_xor((int)x1, 32, 64);      \
      union { unsigned int u[4]; f16x8 v; } bp;                               \
      if (hf == 0) {                                                          \
        bp.u[0] = DW[4 * s2 + 0]; bp.u[1] = DW[4 * s2 + 1];                   \
        bp.u[2] = y0;             bp.u[3] = y1;                               \
      } else {                                                                \
        bp.u[0] = y0;             bp.u[1] = y1;                               \
        bp.u[2] = DW[4 * s2 + 2]; bp.u[3] = DW[4 * s2 + 3];                   \
      }                                                                       \
      const int kchunk = (T) * 4 + s2 * 2 + hf;                               \
      const f16x8 av0 = *(const f16x8*)&Vlds[cur][((vrow0 << 3) | (kchunk ^ vkey0)) * 8]; \
      O0 = __builtin_amdgcn_mfma_f32_32x32x16_f16(av0, bp.v, O0, 0, 0, 0);    \
      const f16x8 av1 = *(const f16x8*)&Vlds[cur][((vrow1 << 3) | (kchunk ^ vkey1)) * 8]; \
      O1 = __builtin_amdgcn_mfma_f32_32x32x16_f16(av1, bp.v, O1, 0, 0, 0);    \
    }                                                                         \
  }

  stage(0, 0);                                // prologue (only exposed latency)

  int cur = 0;
#pragma unroll 2
  for (int s = 0; s < 16; s++) {
    __syncthreads();                          // drains own vmcnt -> buf[cur] ready
    if (s + 1 < 16) stage(s + 1, cur ^ 1);    // in flight under compute(s)

    // bias -> S accumulators for BOTH t tiles (MFMA C-in; off critical path)
    const float* lb0 = &BiasLds[cur][(w + 1) * 63 + idxb];   // t=0
    const float* lb1 = &BiasLds[cur][w * 63 + idxb];         // t=1
    f32x16 S0, S1;
#pragma unroll
    for (int g = 0; g < 4; g++) {
      S0[4 * g + 0] = lb0[-8 * g - 0];
      S0[4 * g + 1] = lb0[-8 * g - 1];
      S0[4 * g + 2] = lb0[-8 * g - 2];
      S0[4 * g + 3] = lb0[-8 * g - 3];
      S1[4 * g + 0] = lb1[-8 * g - 0];
      S1[4 * g + 1] = lb1[-8 * g - 1];
      S1[4 * g + 2] = lb1[-8 * g - 2];
      S1[4 * g + 3] = lb1[-8 * g - 3];
    }

    // S^T MFMAs for both tiles back-to-back (t0 rows ql, t1 rows 32+ql)
    __builtin_amdgcn_s_setprio(1);
#pragma unroll
    for (int ss = 0; ss < 4; ss++) {
      const f16x8 ak = *(const f16x8*)&Klds[cur][((arow0 << 3) | ((ss * 2 + hf) ^ akey0)) * 8];
      S0 = __builtin_amdgcn_mfma_f32_32x32x16_f16(ak, bq[ss], S0, 0, 0, 0);
    }
#pragma unroll
    for (int ss = 0; ss < 4; ss++) {
      const f16x8 ak = *(const f16x8*)&Klds[cur][((arow1 << 3) | ((ss * 2 + hf) ^ akey1)) * 8];
      S1 = __builtin_amdgcn_mfma_f32_32x32x16_f16(ak, bq[ss], S1, 0, 0, 0);
    }
    __builtin_amdgcn_s_setprio(0);

    // pipeline: sm0 (covers S1 latency) -> PV0 -> sm1 (under PV0) -> PV1
    unsigned int dw0[8], dw1[8];
    SOFTMAX(S0, dw0);
    __builtin_amdgcn_s_setprio(1);
    PVACC(dw0, 0);
    __builtin_amdgcn_s_setprio(0);
    SOFTMAX(S1, dw1);
    __builtin_amdgcn_s_setprio(1);
    PVACC(dw1, 1);
    __builtin_amdgcn_s_setprio(0);

    cur ^= 1;
  }

  // total row-sum for this lane's q column; divide + store O^T
  psum += __shfl_xor(psum, 32, 64);
  const float inv = 1.f / psum;
  _Float16* aoRow = AO + ((size_t)(b * NSEQ + qglob)) * DIMC + head * HD;
#pragma unroll
  for (int g = 0; g < 4; g++) {
    f16x4 o0, o1;
#pragma unroll
    for (int j = 0; j < 4; j++) {
      o0[j] = (_Float16)(O0[4 * g + j] * inv);
      o1[j] = (_Float16)(O1[4 * g + j] * inv);
    }
    const int d0 = 8 * g + 4 * hf;
    *(f16x4*)(aoRow + d0) = o0;
    *(f16x4*)(aoRow + 32 + d0) = o1;
  }
}

extern "C" void kernel_launch(void* const* d_in, const int* in_sizes, int n_in,
                              void* d_out, int out_size, void* d_ws, size_t ws_size,
                              hipStream_t stream) {
  const float* x        = (const float*)d_in[0];
  const float* qkv_w    = (const float*)d_in[1];
  const float* q_bias   = (const float*)d_in[2];
  const float* v_bias   = (const float*)d_in[3];
  const float* proj_w   = (const float*)d_in[4];
  const float* proj_b   = (const float*)d_in[5];
  const float* rel_tab  = (const float*)d_in[6];
  float* out = (float*)d_out;

  const size_t NTOK = (size_t)8 * NHH * NSEQ * HD;
  _Float16* Xb     = (_Float16*)d_ws;
  _Float16* Wqkvb  = Xb + SX;
  _Float16* Wprojb = Wqkvb + SW1;
  _Float16* Qb     = Wprojb + SW2;
  _Float16* Kb     = Qb + NTOK;
  _Float16* Vt     = Kb + NTOK;             // V written transposed by qkv gemm
  float*    relT   = (float*)(Vt + NTOK);   // 12*4032 fp32 = 193 KB
  _Float16* AOb    = Xb;                    // alias: x consumed before flash writes

  cast_f16<<<dim3(NCAST + NRELB), 256, 0, stream>>>(x, qkv_w, proj_w, Xb,
                                                    rel_tab, relT);

  gemm_mfma<0><<<dim3(64 * 36), 256, 0, stream>>>(
      Xb, Wqkvb, q_bias, v_bias, nullptr, Qb, Kb, Vt);

  flash_mfma<<<dim3(768), 256, 0, stream>>>(Qb, Kb, Vt, relT, AOb);

  gemm_mfma<1><<<dim3(64 * 12), 256, 0, stream>>>(
      AOb, Wprojb, proj_b, nullptr, out, nullptr, nullptr, nullptr);
}